// Round 4
// baseline (385.707 us; speedup 1.0000x reference)
//
#include <hip/hip_runtime.h>
#include <hip/hip_bf16.h>
#include <math.h>

// GAT 2-layer. Round 13: R12 (channel-split kg1h) with the pass-1 shuffle
// bug fixed — weight broadcast must use the RELATIVE head index (lane>>5),
// not the absolute head (hbase+lane>>5); pass 1 was reading the next edge's
// weights. Everything else unchanged from R12.

typedef unsigned short u16;
typedef unsigned int u32;
typedef __attribute__((ext_vector_type(8))) short bf16x8;
typedef __attribute__((ext_vector_type(4))) float f32x4;

__device__ __forceinline__ float eluf(float v) { return v > 0.f ? v : expm1f(v); }
__device__ __forceinline__ u16 f2bf(float f) {
    u32 u = __float_as_uint(f);
    u += 0x7fff + ((u >> 16) & 1);          // RNE
    return (u16)(u >> 16);
}
__device__ __forceinline__ float bf2f(u16 u) {
    return __uint_as_float(((u32)u) << 16);
}
// exp(leaky02(e)) = exp2(e * (e>=0 ? log2e : 0.2*log2e))
__device__ __forceinline__ float expleaky(float e) {
    float m = e >= 0.f ? 1.44269504f : 0.28853901f;
    return exp2f(e * m);
}

// ---------------- ksetup: W1 frag swizzle | W2 prep | deg zero -------------
__global__ __launch_bounds__(256) void ksetup(
    const float* __restrict__ W1, const float* __restrict__ W2,
    const float* __restrict__ ats2, const float* __restrict__ atd2,
    u16* __restrict__ w1fh, u16* __restrict__ w1fl,
    float* __restrict__ u, float* __restrict__ v, u16* __restrict__ w2tb,
    int* __restrict__ deg, int N)
{
    const int b = blockIdx.x, tid = threadIdx.x;
    if (b < 64) {
        int idx = b * 256 + tid;
        int j = idx & 7, l = (idx >> 3) & 63, q = (idx >> 9) & 3, ct = idx >> 11;
        int k = q * 32 + (l >> 4) * 8 + j;
        int n = ct * 16 + (l & 15);
        float w = W1[k * 128 + n];
        u16 hv = f2bf(w);
        w1fh[idx] = hv;
        w1fl[idx] = f2bf(w - bf2f(hv));
    } else if (b == 64) {
        if (tid < 128) {
            float su = 0.f, sv = 0.f;
            #pragma unroll
            for (int j = 0; j < 16; ++j) {
                float w = W2[tid * 16 + j];
                su = fmaf(w, ats2[j], su);
                sv = fmaf(w, atd2[j], sv);
                w2tb[j * 128 + tid] = f2bf(w);
            }
            u[tid] = su; v[tid] = sv;
        }
    } else {
        int z = (b - 65) * 1024 + tid * 4;
        if (z < N) *(int4*)&deg[z] = make_int4(0, 0, 0, 0);
    }
}

// ---------------- mega1: heterogeneous khist + persistent GEMM -------------
#define REPW 40   // u16 per repack row (80 B)
__global__ __launch_bounds__(256) void mega1(
    const float* __restrict__ x, const u16* __restrict__ w1fh,
    const u16* __restrict__ w1fl,
    const float* __restrict__ att_s, const float* __restrict__ att_d,
    u16* __restrict__ h1b, float* __restrict__ as1, float* __restrict__ ad1,
    int N,
    const int* __restrict__ ei, int* __restrict__ deg, int* __restrict__ rank,
    int E, int KB)
{
    __shared__ u16 rep[4][16 * REPW];
    const int tid = threadIdx.x;
    const int b = blockIdx.x;

    if (b % 3 == 0) {
        // ---- khist block: 2048 edges, 8 per thread, pipelined atomics ----
        const int base = (b / 3) * 2048 + tid;
        int dd[8];
        #pragma unroll
        for (int k = 0; k < 8; ++k) {
            int e = base + 256 * k;
            dd[k] = (e < E) ? ei[E + e] : -1;
        }
        int rk[8];
        #pragma unroll
        for (int k = 0; k < 8; ++k)
            if (dd[k] >= 0) rk[k] = atomicAdd(&deg[dd[k]], 1);
        #pragma unroll
        for (int k = 0; k < 8; ++k) {
            int e = base + 256 * k;
            if (e < E) rank[e] = rk[k];
        }
        return;
    }

    const int g = b - b / 3 - 1;             // GEMM block index, [0, 2*KB)
    const int GB = 2 * KB;
    const int wv = tid >> 6, lane = tid & 63;
    const int m = lane & 15, quad = lane >> 4;
    const int h = wv;                        // head handled by this wave

    // --- B fragments for this head: cts {2h, 2h+1}, hi+lo ---
    bf16x8 bh[2][4], bl[2][4];
    #pragma unroll
    for (int sub = 0; sub < 2; ++sub) {
        #pragma unroll
        for (int q = 0; q < 4; ++q) {
            const int off = (((2 * h + sub) * 4 + q) * 64 + lane) * 8;
            bh[sub][q] = *(const bf16x8*)&w1fh[off];
            bl[sub][q] = *(const bf16x8*)&w1fl[off];
        }
    }

    const float cs0 = att_s[h * 32 + m];
    const float cs1 = att_s[h * 32 + 16 + m];
    const float cd0 = att_d[h * 32 + m];
    const float cd1 = att_d[h * 32 + 16 + m];

    u16* myrep = rep[wv];
    const int ntile = (N + 15) >> 4;

    for (int t = g; t < ntile; t += GB) {
        const int r0 = t << 4;
        int arow = r0 + m;
        if (arow >= N) arow = N - 1;
        const float* xr = &x[(size_t)arow * 128 + quad * 8];

        // A fragments (hi/lo split), row = r0+m, k = q*32 + quad*8 + j
        bf16x8 ah[4], al[4];
        #pragma unroll
        for (int q = 0; q < 4; ++q) {
            float4 f0 = *(const float4*)&xr[q * 32];
            float4 f1 = *(const float4*)&xr[q * 32 + 4];
            float fv[8] = {f0.x, f0.y, f0.z, f0.w, f1.x, f1.y, f1.z, f1.w};
            union { u16 us[8]; bf16x8 v; } hh, lu;
            #pragma unroll
            for (int j = 0; j < 8; ++j) {
                u16 hvv = f2bf(fv[j]);
                hh.us[j] = hvv;
                lu.us[j] = f2bf(fv[j] - bf2f(hvv));
            }
            ah[q] = hh.v; al[q] = lu.v;
        }

        f32x4 acc[2];
        #pragma unroll
        for (int sub = 0; sub < 2; ++sub) {
            f32x4 a = {0.f, 0.f, 0.f, 0.f};
            #pragma unroll
            for (int q = 0; q < 4; ++q) {
                a = __builtin_amdgcn_mfma_f32_16x16x32_bf16(ah[q], bh[sub][q], a, 0, 0, 0);
                a = __builtin_amdgcn_mfma_f32_16x16x32_bf16(al[q], bh[sub][q], a, 0, 0, 0);
                a = __builtin_amdgcn_mfma_f32_16x16x32_bf16(ah[q], bl[sub][q], a, 0, 0, 0);
            }
            acc[sub] = a;
        }

        // attention dots for this head: col = h*32 + sub*16 + m
        float sp[4], dp[4];
        #pragma unroll
        for (int r = 0; r < 4; ++r) {
            sp[r] = fmaf(acc[0][r], cs0, acc[1][r] * cs1);
            dp[r] = fmaf(acc[0][r], cd0, acc[1][r] * cd1);
        }
        #pragma unroll
        for (int r = 0; r < 4; ++r) {
            sp[r] += __shfl_xor(sp[r], 1); sp[r] += __shfl_xor(sp[r], 2);
            sp[r] += __shfl_xor(sp[r], 4); sp[r] += __shfl_xor(sp[r], 8);
            dp[r] += __shfl_xor(dp[r], 1); dp[r] += __shfl_xor(dp[r], 2);
            dp[r] += __shfl_xor(dp[r], 4); dp[r] += __shfl_xor(dp[r], 8);
        }
        if (m == 0) {
            #pragma unroll
            for (int r = 0; r < 4; ++r) {
                int rr = r0 + quad * 4 + r;
                if (rr < N) {
                    as1[rr * 4 + h] = sp[r];
                    ad1[rr * 4 + h] = dp[r];
                }
            }
        }

        // repack -> coalesced h1b stores; wave-synchronous LDS slice.
        #pragma unroll
        for (int sub = 0; sub < 2; ++sub) {
            #pragma unroll
            for (int r = 0; r < 4; ++r)
                myrep[(quad * 4 + r) * REPW + sub * 16 + m] = f2bf(acc[sub][r]);
        }
        __asm__ __volatile__("s_waitcnt lgkmcnt(0)" ::: "memory");
        __builtin_amdgcn_sched_barrier(0);
        const int rr = lane >> 2, cc = lane & 3;
        uint4 vv = *(const uint4*)&myrep[rr * REPW + cc * 8];
        const int grow = r0 + rr;
        if (grow < N)
            *(uint4*)&h1b[(size_t)grow * 128 + h * 32 + cc * 8] = vv;
    }
}

// ---------------- kscan1 / kscan2 ------------------------------------------
__global__ __launch_bounds__(256) void kscan1(
    const int* __restrict__ deg, int* __restrict__ rowptr,
    int* __restrict__ bsum, int N)
{
    __shared__ int lds[256];
    const int t = threadIdx.x;
    const int base = blockIdx.x * 1024 + t * 4;
    int v[4];
    int s = 0;
    #pragma unroll
    for (int j = 0; j < 4; ++j) {
        v[j] = (base + j < N) ? deg[base + j] : 0;
        s += v[j];
    }
    lds[t] = s;
    __syncthreads();
    for (int off = 1; off < 256; off <<= 1) {
        int y = (t >= off) ? lds[t - off] : 0;
        __syncthreads();
        lds[t] += y;
        __syncthreads();
    }
    int run = lds[t] - s;
    #pragma unroll
    for (int j = 0; j < 4; ++j) {
        if (base + j < N) rowptr[base + j] = run;
        run += v[j];
    }
    if (t == 255) bsum[blockIdx.x] = lds[255];
}

__global__ __launch_bounds__(128) void kscan2(int* __restrict__ bsum, int NB)
{
    __shared__ int lds[128];
    const int t = threadIdx.x;
    int v = (t < NB) ? bsum[t] : 0;
    lds[t] = v;
    __syncthreads();
    for (int off = 1; off < 128; off <<= 1) {
        int y = (t >= off) ? lds[t - off] : 0;
        __syncthreads();
        lds[t] += y;
        __syncthreads();
    }
    if (t < NB) bsum[t] = lds[t] - v;
}

// ---------------- kscat: colidx-only scatter -------------------------------
__global__ __launch_bounds__(256) void kscat(
    const int* __restrict__ ei, const int* __restrict__ rowptr,
    const int* __restrict__ bsum, const int* __restrict__ rank,
    int* __restrict__ colidx, int E)
{
    int e = blockIdx.x * 256 + threadIdx.x;
    if (e >= E) return;
    int s = ei[e], d = ei[E + e];
    colidx[rowptr[d] + bsum[d >> 10] + rank[e]] = s;
}

// ---------------- KG1H: layer-1 gather, one channel-half per pass ----------
// coff = 0 (heads 0,1) or 64 (heads 2,3). Per lane: channel c = coff+lane
// (ushort gather, 128 B/wave-instr). Weight pre-pass covers 32 edges x 2
// heads per block: lane l holds edge l>>1, head hbase+(l&1). Broadcast for
// edge e, head hh uses RELATIVE head index hsel = lane>>5 (bug fixed here).
// Pass 1 adds its as2/ad2 dot partials on top of pass 0's (stream-ordered).
__global__ __launch_bounds__(256) void kg1h(
    const int* __restrict__ rowptr, const int* __restrict__ bsum,
    const int* __restrict__ colidx,
    const u16* __restrict__ h1b, const float* __restrict__ as1,
    const float* __restrict__ ad1, const float* __restrict__ b1,
    const float* __restrict__ u, const float* __restrict__ v,
    u16* __restrict__ x2b, float* __restrict__ as2, float* __restrict__ ad2,
    int N, int E, int coff)
{
    const int d = blockIdx.x * 4 + (threadIdx.x >> 6);
    if (d >= N) return;
    const int lane = threadIdx.x & 63;
    const int hbase = coff >> 5;               // 0 or 2
    const int hsel = lane >> 5;                // 0/1: relative head of lane
    const int hh = hbase + hsel;               // absolute head of this lane
    const int headA = hbase + (lane & 1);      // head slot in weight pre-pass
    const int eA = lane >> 1;                  // edge slot in weight pre-pass
    const int c = coff + lane;                 // channel of this lane

    const float adA = ad1[d * 4 + headA];
    const float wself = expleaky(as1[d * 4 + hh] + ad1[d * 4 + hh]);
    float acc = wself * bf2f(h1b[(d << 7) + c]);
    float den = wself;

    int i0r = rowptr[d] + bsum[d >> 10];
    int i1r = (d + 1 == N) ? E : rowptr[d + 1] + bsum[(d + 1) >> 10];
    const int i0 = __builtin_amdgcn_readfirstlane(i0r);
    const int i1 = __builtin_amdgcn_readfirstlane(i1r);

    const u16* hp = h1b + c;                   // gather base for this lane

    for (int i = i0; i < i1; i += 32) {
        const int nb = min(32, i1 - i);
        const int ii = i + eA;
        const int iic = ii < i1 ? ii : i0;
        int sAv = colidx[iic];
        float wA = expleaky(as1[(sAv << 2) + headA] + adA);
        wA = (ii < i1) ? wA : 0.f;
        int e = 0;
        for (; e + 8 <= nb; e += 8) {
            int s0 = colidx[i + e + 0];
            int s1 = colidx[i + e + 1];
            int s2 = colidx[i + e + 2];
            int s3 = colidx[i + e + 3];
            int s4 = colidx[i + e + 4];
            int s5 = colidx[i + e + 5];
            int s6 = colidx[i + e + 6];
            int s7 = colidx[i + e + 7];
            float w0 = __shfl(wA, ((e + 0) << 1) + hsel);
            float w1 = __shfl(wA, ((e + 1) << 1) + hsel);
            float w2 = __shfl(wA, ((e + 2) << 1) + hsel);
            float w3 = __shfl(wA, ((e + 3) << 1) + hsel);
            float w4 = __shfl(wA, ((e + 4) << 1) + hsel);
            float w5 = __shfl(wA, ((e + 5) << 1) + hsel);
            float w6 = __shfl(wA, ((e + 6) << 1) + hsel);
            float w7 = __shfl(wA, ((e + 7) << 1) + hsel);
            u16 v0 = hp[s0 << 7];
            u16 v1 = hp[s1 << 7];
            u16 v2 = hp[s2 << 7];
            u16 v3 = hp[s3 << 7];
            u16 v4 = hp[s4 << 7];
            u16 v5 = hp[s5 << 7];
            u16 v6 = hp[s6 << 7];
            u16 v7 = hp[s7 << 7];
            acc = fmaf(w0, bf2f(v0), acc);
            acc = fmaf(w1, bf2f(v1), acc);
            acc = fmaf(w2, bf2f(v2), acc);
            acc = fmaf(w3, bf2f(v3), acc);
            acc = fmaf(w4, bf2f(v4), acc);
            acc = fmaf(w5, bf2f(v5), acc);
            acc = fmaf(w6, bf2f(v6), acc);
            acc = fmaf(w7, bf2f(v7), acc);
            den += ((w0 + w1) + (w2 + w3)) + ((w4 + w5) + (w6 + w7));
        }
        for (; e < nb; ++e) {
            int s = colidx[i + e];
            float w = __shfl(wA, (e << 1) + hsel);
            acc = fmaf(w, bf2f(hp[s << 7]), acc);
            den += w;
        }
    }

    const float inv = 1.f / den;
    const float x2v = eluf(fmaf(acc, inv, b1[c]));

    x2b[(d << 7) + c] = f2bf(x2v);

    float sA = x2v * u[c];
    float sB = x2v * v[c];
    #pragma unroll
    for (int m = 1; m < 64; m <<= 1) {
        sA += __shfl_xor(sA, m);
        sB += __shfl_xor(sB, m);
    }
    if (lane == 0) {
        if (coff == 0) { as2[d] = sA; ad2[d] = sB; }
        else { as2[d] += sA; ad2[d] += sB; }
    }
}

// ---------------- KH2: h2 = x2 @ W2 via MFMA (bf16 out) --------------------
__global__ __launch_bounds__(256) void kh2(
    const u16* __restrict__ x2b, const u16* __restrict__ w2tb,
    u16* __restrict__ h2b, int N)
{
    const int wv = threadIdx.x >> 6, lane = threadIdx.x & 63;
    const int n0 = blockIdx.x * 64 + wv * 16;
    if (n0 >= N) return;
    const int m = lane & 15;
    const int kq = lane >> 4;
    bf16x8 bfr[4];
    #pragma unroll
    for (int q = 0; q < 4; ++q)
        bfr[q] = *(const bf16x8*)&w2tb[m * 128 + q * 32 + kq * 8];

    int ar = n0 + m;
    if (ar >= N) ar = N - 1;
    const u16* arow = &x2b[((size_t)ar << 7) + kq * 8];
    f32x4 acc = {0.f, 0.f, 0.f, 0.f};
    #pragma unroll
    for (int q = 0; q < 4; ++q) {
        bf16x8 af = *(const bf16x8*)&arow[q * 32];
        acc = __builtin_amdgcn_mfma_f32_16x16x32_bf16(af, bfr[q], acc, 0, 0, 0);
    }
    #pragma unroll
    for (int r = 0; r < 4; ++r) {
        int rr = n0 + kq * 4 + r;
        if (rr < N) h2b[((size_t)rr << 4) + m] = f2bf(acc[r]);
    }
}

// ---------------- KG2: layer-2 gather, in-wave weights ---------------------
__global__ __launch_bounds__(256) void kg2(
    const int* __restrict__ rowptr, const int* __restrict__ bsum,
    const int* __restrict__ colidx,
    const u16* __restrict__ h2b, const float* __restrict__ as2,
    const float* __restrict__ ad2, const float* __restrict__ b2,
    float* __restrict__ out, int N, int E)
{
    const int d = blockIdx.x * 4 + (threadIdx.x >> 6);
    if (d >= N) return;
    const int lane = threadIdx.x & 63;
    const int ch = lane & 7, g = lane >> 3;

    const float ad_d = ad2[d];
    float acc0 = 0.f, acc1 = 0.f, den = 0.f;
    int i0r = rowptr[d] + bsum[d >> 10];
    int i1r = (d + 1 == N) ? E : rowptr[d + 1] + bsum[(d + 1) >> 10];
    const int i0 = __builtin_amdgcn_readfirstlane(i0r);
    const int i1 = __builtin_amdgcn_readfirstlane(i1r);

    for (int i = i0; i < i1; i += 64) {
        const int nb = min(64, i1 - i);
        const int idx = i + lane;
        const int idxc = idx < i1 ? idx : i0;
        int sA = colidx[idxc];
        float wA = expleaky(as2[sA] + ad_d);
        wA = (idx < i1) ? wA : 0.f;
        const int kU = (nb + 7) >> 3;
        for (int k = 0; k < kU; ++k) {
            int e = g + 8 * k;
            int ec = e < nb ? e : 0;
            float w = __shfl(wA, ec);
            int s = __shfl(sA, ec);
            if (e >= nb) w = 0.f;
            u32 hv = *(const u32*)&h2b[(s << 4) + ch * 2];
            acc0 = fmaf(w, bf2f((u16)hv), acc0);
            acc1 = fmaf(w, bf2f((u16)(hv >> 16)), acc1);
            den += w;
        }
    }
    acc0 += __shfl_xor(acc0, 8); acc0 += __shfl_xor(acc0, 16); acc0 += __shfl_xor(acc0, 32);
    acc1 += __shfl_xor(acc1, 8); acc1 += __shfl_xor(acc1, 16); acc1 += __shfl_xor(acc1, 32);
    den  += __shfl_xor(den, 8);  den  += __shfl_xor(den, 16);  den  += __shfl_xor(den, 32);

    const float wself = expleaky(as2[d] + ad_d);
    u32 hd = *(const u32*)&h2b[(d << 4) + ch * 2];
    acc0 = fmaf(wself, bf2f((u16)hd), acc0);
    acc1 = fmaf(wself, bf2f((u16)(hd >> 16)), acc1);
    den += wself;
    if (g == 0) {
        float2 ov = {acc0 / den + b2[ch * 2], acc1 / den + b2[ch * 2 + 1]};
        *(float2*)&out[(d << 4) + ch * 2] = ov;
    }
}

extern "C" void kernel_launch(void* const* d_in, const int* in_sizes, int n_in,
                              void* d_out, int out_size, void* d_ws, size_t ws_size,
                              hipStream_t stream) {
    const float* x    = (const float*)d_in[0];
    const int*   ei   = (const int*)d_in[1];
    const float* W1   = (const float*)d_in[2];
    const float* ats1 = (const float*)d_in[3];
    const float* atd1 = (const float*)d_in[4];
    const float* b1   = (const float*)d_in[5];
    const float* W2   = (const float*)d_in[6];
    const float* ats2 = (const float*)d_in[7];
    const float* atd2 = (const float*)d_in[8];
    const float* b2   = (const float*)d_in[9];
    float* out = (float*)d_out;
    const int N = in_sizes[0] / 128;
    const int E = in_sizes[1] / 2;

    u16* h1b   = (u16*)d_ws;                        // 128N
    u16* x2b   = h1b + (size_t)N * 128;             // 128N
    u16* h2b   = x2b + (size_t)N * 128;             // 16N
    u16* w2tb  = h2b + (size_t)N * 16;              // 2048
    u16* w1fh  = w2tb + 2048;                       // 16384
    u16* w1fl  = w1fh + 16384;                      // 16384
    float* as1 = (float*)(w1fl + 16384);            // 4N
    float* ad1 = as1 + (size_t)N * 4;               // 4N
    float* as2 = ad1 + (size_t)N * 4;               // N
    float* ad2 = as2 + N;                           // N
    float* u   = ad2 + N;                           // 128
    float* v   = u + 128;                           // 128
    int* deg    = (int*)(v + 128);                  // N (padded)
    int* rowptr = deg + ((N + 7) & ~3);             // N+1 (padded)
    int* bsum   = rowptr + ((N + 7) & ~3);          // 128
    int* colidx = bsum + 128;                       // E
    int* rank   = colidx + E;                       // E

    const int NB = (N + 1023) / 1024;
    const int KB = (E + 2047) / 2048;               // khist blocks
    const int G1 = 3 * KB;                          // total mega1 grid

    hipLaunchKernelGGL(ksetup, dim3(65 + NB), dim3(256), 0, stream,
                       W1, W2, ats2, atd2, w1fh, w1fl, u, v, w2tb, deg, N);
    hipLaunchKernelGGL(mega1, dim3(G1), dim3(256), 0, stream,
                       x, w1fh, w1fl, ats1, atd1, h1b, as1, ad1, N,
                       ei, deg, rank, E, KB);
    hipLaunchKernelGGL(kscan1, dim3(NB), dim3(256), 0, stream,
                       deg, rowptr, bsum, N);
    hipLaunchKernelGGL(kscan2, dim3(1), dim3(128), 0, stream, bsum, NB);
    hipLaunchKernelGGL(kscat, dim3((E + 255) / 256), dim3(256), 0, stream,
                       ei, rowptr, bsum, rank, colidx, E);
    hipLaunchKernelGGL(kg1h, dim3((N + 3) / 4), dim3(256), 0, stream,
                       rowptr, bsum, colidx, h1b, as1, ad1, b1, u, v,
                       x2b, as2, ad2, N, E, 0);
    hipLaunchKernelGGL(kg1h, dim3((N + 3) / 4), dim3(256), 0, stream,
                       rowptr, bsum, colidx, h1b, as1, ad1, b1, u, v,
                       x2b, as2, ad2, N, E, 64);
    hipLaunchKernelGGL(kh2, dim3((N + 63) / 64), dim3(256), 0, stream,
                       x2b, w2tb, h2b, N);
    hipLaunchKernelGGL(kg2, dim3((N + 3) / 4), dim3(256), 0, stream,
                       rowptr, bsum, colidx, h2b, as2, ad2, b2, out, N, E);
}

// Round 5
// 365.529 us; speedup vs baseline: 1.0552x; 1.0552x over previous
//
#include <hip/hip_runtime.h>
#include <hip/hip_bf16.h>
#include <math.h>

// GAT 2-layer. Round 14: ablation-by-fission. mega1 split into khist (pure
// atomic histogram, own dispatch, full occupancy) and kgemm (pure MFMA GEMM,
// B-fragments pinned in VGPRs with empty asm so the compiler cannot sink the
// weight loads back into the tile loop — R13's VGPR_Count=80 proved they
// were NOT register-resident). kg1h channel-split reverted to R11's
// single-pass kg1 (split regressed: same instr count, 2x overhead).
// Pre-committed read: khist >= 40 us => atomics fabric-bound => R15 rewrites
// CSR build; khist <= 15 us => latency was the issue, tune kgemm next.

typedef unsigned short u16;
typedef unsigned int u32;
typedef __attribute__((ext_vector_type(8))) short bf16x8;
typedef __attribute__((ext_vector_type(4))) float f32x4;

__device__ __forceinline__ float eluf(float v) { return v > 0.f ? v : expm1f(v); }
__device__ __forceinline__ u16 f2bf(float f) {
    u32 u = __float_as_uint(f);
    u += 0x7fff + ((u >> 16) & 1);          // RNE
    return (u16)(u >> 16);
}
__device__ __forceinline__ float bf2f(u16 u) {
    return __uint_as_float(((u32)u) << 16);
}
// exp(leaky02(e)) = exp2(e * (e>=0 ? log2e : 0.2*log2e))
__device__ __forceinline__ float expleaky(float e) {
    float m = e >= 0.f ? 1.44269504f : 0.28853901f;
    return exp2f(e * m);
}

// ---------------- ksetup: W1 frag swizzle | W2 prep | deg zero -------------
__global__ __launch_bounds__(256) void ksetup(
    const float* __restrict__ W1, const float* __restrict__ W2,
    const float* __restrict__ ats2, const float* __restrict__ atd2,
    u16* __restrict__ w1fh, u16* __restrict__ w1fl,
    float* __restrict__ u, float* __restrict__ v, u16* __restrict__ w2tb,
    int* __restrict__ deg, int N)
{
    const int b = blockIdx.x, tid = threadIdx.x;
    if (b < 64) {
        int idx = b * 256 + tid;
        int j = idx & 7, l = (idx >> 3) & 63, q = (idx >> 9) & 3, ct = idx >> 11;
        int k = q * 32 + (l >> 4) * 8 + j;
        int n = ct * 16 + (l & 15);
        float w = W1[k * 128 + n];
        u16 hv = f2bf(w);
        w1fh[idx] = hv;
        w1fl[idx] = f2bf(w - bf2f(hv));
    } else if (b == 64) {
        if (tid < 128) {
            float su = 0.f, sv = 0.f;
            #pragma unroll
            for (int j = 0; j < 16; ++j) {
                float w = W2[tid * 16 + j];
                su = fmaf(w, ats2[j], su);
                sv = fmaf(w, atd2[j], sv);
                w2tb[j * 128 + tid] = f2bf(w);
            }
            u[tid] = su; v[tid] = sv;
        }
    } else {
        int z = (b - 65) * 1024 + tid * 4;
        if (z < N) *(int4*)&deg[z] = make_int4(0, 0, 0, 0);
    }
}

// ---------------- khist: standalone pipelined atomic histogram -------------
__global__ __launch_bounds__(256) void khist(
    const int* __restrict__ ei, int* __restrict__ deg, int* __restrict__ rank,
    int E)
{
    const int base = blockIdx.x * 2048 + threadIdx.x;
    int dd[8];
    #pragma unroll
    for (int k = 0; k < 8; ++k) {
        int e = base + 256 * k;
        dd[k] = (e < E) ? ei[E + e] : -1;
    }
    int rk[8];
    #pragma unroll
    for (int k = 0; k < 8; ++k)
        if (dd[k] >= 0) rk[k] = atomicAdd(&deg[dd[k]], 1);
    #pragma unroll
    for (int k = 0; k < 8; ++k) {
        int e = base + 256 * k;
        if (e < E) rank[e] = rk[k];
    }
}

// ---------------- kgemm: persistent GEMM, pinned B-fragments ---------------
#define REPW 40   // u16 per repack row (80 B)
__global__ __launch_bounds__(256) void kgemm(
    const float* __restrict__ x, const u16* __restrict__ w1fh,
    const u16* __restrict__ w1fl,
    const float* __restrict__ att_s, const float* __restrict__ att_d,
    u16* __restrict__ h1b, float* __restrict__ as1, float* __restrict__ ad1,
    int N, int GB)
{
    __shared__ u16 rep[4][16 * REPW];
    const int tid = threadIdx.x;
    const int wv = tid >> 6, lane = tid & 63;
    const int m = lane & 15, quad = lane >> 4;
    const int h = wv;                        // head handled by this wave

    // --- B fragments for this head: cts {2h, 2h+1}, hi+lo ---
    bf16x8 bh[2][4], bl[2][4];
    #pragma unroll
    for (int sub = 0; sub < 2; ++sub) {
        #pragma unroll
        for (int q = 0; q < 4; ++q) {
            const int off = (((2 * h + sub) * 4 + q) * 64 + lane) * 8;
            bh[sub][q] = *(const bf16x8*)&w1fh[off];
            bl[sub][q] = *(const bf16x8*)&w1fl[off];
        }
    }
    // Pin the fragments: opaque asm forces them to live in VGPRs across the
    // whole tile loop (compiler cannot re-sink the loads into the loop).
    #pragma unroll
    for (int sub = 0; sub < 2; ++sub) {
        #pragma unroll
        for (int q = 0; q < 4; ++q) {
            asm volatile("" : "+v"(bh[sub][q]));
            asm volatile("" : "+v"(bl[sub][q]));
        }
    }

    const float cs0 = att_s[h * 32 + m];
    const float cs1 = att_s[h * 32 + 16 + m];
    const float cd0 = att_d[h * 32 + m];
    const float cd1 = att_d[h * 32 + 16 + m];

    u16* myrep = rep[wv];
    const int ntile = (N + 15) >> 4;

    for (int t = blockIdx.x; t < ntile; t += GB) {
        const int r0 = t << 4;
        int arow = r0 + m;
        if (arow >= N) arow = N - 1;
        const float* xr = &x[(size_t)arow * 128 + quad * 8];

        // A fragments (hi/lo split), row = r0+m, k = q*32 + quad*8 + j
        bf16x8 ah[4], al[4];
        #pragma unroll
        for (int q = 0; q < 4; ++q) {
            float4 f0 = *(const float4*)&xr[q * 32];
            float4 f1 = *(const float4*)&xr[q * 32 + 4];
            float fv[8] = {f0.x, f0.y, f0.z, f0.w, f1.x, f1.y, f1.z, f1.w};
            union { u16 us[8]; bf16x8 v; } hh, lu;
            #pragma unroll
            for (int j = 0; j < 8; ++j) {
                u16 hvv = f2bf(fv[j]);
                hh.us[j] = hvv;
                lu.us[j] = f2bf(fv[j] - bf2f(hvv));
            }
            ah[q] = hh.v; al[q] = lu.v;
        }

        f32x4 acc[2];
        #pragma unroll
        for (int sub = 0; sub < 2; ++sub) {
            f32x4 a = {0.f, 0.f, 0.f, 0.f};
            #pragma unroll
            for (int q = 0; q < 4; ++q) {
                a = __builtin_amdgcn_mfma_f32_16x16x32_bf16(ah[q], bh[sub][q], a, 0, 0, 0);
                a = __builtin_amdgcn_mfma_f32_16x16x32_bf16(al[q], bh[sub][q], a, 0, 0, 0);
                a = __builtin_amdgcn_mfma_f32_16x16x32_bf16(ah[q], bl[sub][q], a, 0, 0, 0);
            }
            acc[sub] = a;
        }

        // attention dots for this head: col = h*32 + sub*16 + m
        float sp[4], dp[4];
        #pragma unroll
        for (int r = 0; r < 4; ++r) {
            sp[r] = fmaf(acc[0][r], cs0, acc[1][r] * cs1);
            dp[r] = fmaf(acc[0][r], cd0, acc[1][r] * cd1);
        }
        #pragma unroll
        for (int r = 0; r < 4; ++r) {
            sp[r] += __shfl_xor(sp[r], 1); sp[r] += __shfl_xor(sp[r], 2);
            sp[r] += __shfl_xor(sp[r], 4); sp[r] += __shfl_xor(sp[r], 8);
            dp[r] += __shfl_xor(dp[r], 1); dp[r] += __shfl_xor(dp[r], 2);
            dp[r] += __shfl_xor(dp[r], 4); dp[r] += __shfl_xor(dp[r], 8);
        }
        if (m == 0) {
            #pragma unroll
            for (int r = 0; r < 4; ++r) {
                int rr = r0 + quad * 4 + r;
                if (rr < N) {
                    as1[rr * 4 + h] = sp[r];
                    ad1[rr * 4 + h] = dp[r];
                }
            }
        }

        // repack -> coalesced h1b stores; wave-synchronous LDS slice.
        #pragma unroll
        for (int sub = 0; sub < 2; ++sub) {
            #pragma unroll
            for (int r = 0; r < 4; ++r)
                myrep[(quad * 4 + r) * REPW + sub * 16 + m] = f2bf(acc[sub][r]);
        }
        __asm__ __volatile__("s_waitcnt lgkmcnt(0)" ::: "memory");
        __builtin_amdgcn_sched_barrier(0);
        const int rr = lane >> 2, cc = lane & 3;
        uint4 vv = *(const uint4*)&myrep[rr * REPW + cc * 8];
        const int grow = r0 + rr;
        if (grow < N)
            *(uint4*)&h1b[(size_t)grow * 128 + h * 32 + cc * 8] = vv;
    }
}

// ---------------- kscan1 / kscan2 ------------------------------------------
__global__ __launch_bounds__(256) void kscan1(
    const int* __restrict__ deg, int* __restrict__ rowptr,
    int* __restrict__ bsum, int N)
{
    __shared__ int lds[256];
    const int t = threadIdx.x;
    const int base = blockIdx.x * 1024 + t * 4;
    int v[4];
    int s = 0;
    #pragma unroll
    for (int j = 0; j < 4; ++j) {
        v[j] = (base + j < N) ? deg[base + j] : 0;
        s += v[j];
    }
    lds[t] = s;
    __syncthreads();
    for (int off = 1; off < 256; off <<= 1) {
        int y = (t >= off) ? lds[t - off] : 0;
        __syncthreads();
        lds[t] += y;
        __syncthreads();
    }
    int run = lds[t] - s;
    #pragma unroll
    for (int j = 0; j < 4; ++j) {
        if (base + j < N) rowptr[base + j] = run;
        run += v[j];
    }
    if (t == 255) bsum[blockIdx.x] = lds[255];
}

__global__ __launch_bounds__(128) void kscan2(int* __restrict__ bsum, int NB)
{
    __shared__ int lds[128];
    const int t = threadIdx.x;
    int v = (t < NB) ? bsum[t] : 0;
    lds[t] = v;
    __syncthreads();
    for (int off = 1; off < 128; off <<= 1) {
        int y = (t >= off) ? lds[t - off] : 0;
        __syncthreads();
        lds[t] += y;
        __syncthreads();
    }
    if (t < NB) bsum[t] = lds[t] - v;
}

// ---------------- kscat: colidx-only scatter -------------------------------
__global__ __launch_bounds__(256) void kscat(
    const int* __restrict__ ei, const int* __restrict__ rowptr,
    const int* __restrict__ bsum, const int* __restrict__ rank,
    int* __restrict__ colidx, int E)
{
    int e = blockIdx.x * 256 + threadIdx.x;
    if (e >= E) return;
    int s = ei[e], d = ei[E + e];
    colidx[rowptr[d] + bsum[d >> 10] + rank[e]] = s;
}

// ---------------- KG1: layer-1 gather, in-wave weights ---------------------
__global__ __launch_bounds__(256) void kg1(
    const int* __restrict__ rowptr, const int* __restrict__ bsum,
    const int* __restrict__ colidx,
    const u16* __restrict__ h1b, const float* __restrict__ as1,
    const float* __restrict__ ad1, const float* __restrict__ b1,
    const float* __restrict__ u, const float* __restrict__ v,
    u16* __restrict__ x2b, float* __restrict__ as2, float* __restrict__ ad2,
    int N, int E)
{
    const int d = blockIdx.x * 4 + (threadIdx.x >> 6);
    if (d >= N) return;
    const int lane = threadIdx.x & 63;
    const int c = lane * 2;
    const int headB = lane >> 4;
    const int headA = lane & 3;
    const int eA = lane >> 2;

    const float adA = ad1[d * 4 + headA];
    const float wself = expleaky(as1[d * 4 + headB] + ad1[d * 4 + headB]);
    u32 hd = *(const u32*)&h1b[(d << 7) + c];
    float accx = wself * bf2f((u16)hd);
    float accy = wself * bf2f((u16)(hd >> 16));
    float den = wself;

    int i0r = rowptr[d] + bsum[d >> 10];
    int i1r = (d + 1 == N) ? E : rowptr[d + 1] + bsum[(d + 1) >> 10];
    const int i0 = __builtin_amdgcn_readfirstlane(i0r);
    const int i1 = __builtin_amdgcn_readfirstlane(i1r);

    for (int i = i0; i < i1; i += 16) {
        const int nb = min(16, i1 - i);
        const int ii = i + eA;
        const int iic = ii < i1 ? ii : i0;
        int sAv = colidx[iic];
        float wA = expleaky(as1[(sAv << 2) + headA] + adA);
        wA = (ii < i1) ? wA : 0.f;
        int e = 0;
        for (; e + 8 <= nb; e += 8) {
            int s0 = colidx[i + e + 0];
            int s1 = colidx[i + e + 1];
            int s2 = colidx[i + e + 2];
            int s3 = colidx[i + e + 3];
            int s4 = colidx[i + e + 4];
            int s5 = colidx[i + e + 5];
            int s6 = colidx[i + e + 6];
            int s7 = colidx[i + e + 7];
            float w0 = __shfl(wA, ((e + 0) << 2) + headB);
            float w1 = __shfl(wA, ((e + 1) << 2) + headB);
            float w2 = __shfl(wA, ((e + 2) << 2) + headB);
            float w3 = __shfl(wA, ((e + 3) << 2) + headB);
            float w4 = __shfl(wA, ((e + 4) << 2) + headB);
            float w5 = __shfl(wA, ((e + 5) << 2) + headB);
            float w6 = __shfl(wA, ((e + 6) << 2) + headB);
            float w7 = __shfl(wA, ((e + 7) << 2) + headB);
            u32 v0 = *(const u32*)&h1b[(s0 << 7) + c];
            u32 v1 = *(const u32*)&h1b[(s1 << 7) + c];
            u32 v2 = *(const u32*)&h1b[(s2 << 7) + c];
            u32 v3 = *(const u32*)&h1b[(s3 << 7) + c];
            u32 v4 = *(const u32*)&h1b[(s4 << 7) + c];
            u32 v5 = *(const u32*)&h1b[(s5 << 7) + c];
            u32 v6 = *(const u32*)&h1b[(s6 << 7) + c];
            u32 v7 = *(const u32*)&h1b[(s7 << 7) + c];
            accx = fmaf(w0, bf2f((u16)v0), accx); accy = fmaf(w0, bf2f((u16)(v0 >> 16)), accy);
            accx = fmaf(w1, bf2f((u16)v1), accx); accy = fmaf(w1, bf2f((u16)(v1 >> 16)), accy);
            accx = fmaf(w2, bf2f((u16)v2), accx); accy = fmaf(w2, bf2f((u16)(v2 >> 16)), accy);
            accx = fmaf(w3, bf2f((u16)v3), accx); accy = fmaf(w3, bf2f((u16)(v3 >> 16)), accy);
            accx = fmaf(w4, bf2f((u16)v4), accx); accy = fmaf(w4, bf2f((u16)(v4 >> 16)), accy);
            accx = fmaf(w5, bf2f((u16)v5), accx); accy = fmaf(w5, bf2f((u16)(v5 >> 16)), accy);
            accx = fmaf(w6, bf2f((u16)v6), accx); accy = fmaf(w6, bf2f((u16)(v6 >> 16)), accy);
            accx = fmaf(w7, bf2f((u16)v7), accx); accy = fmaf(w7, bf2f((u16)(v7 >> 16)), accy);
            den += ((w0 + w1) + (w2 + w3)) + ((w4 + w5) + (w6 + w7));
        }
        for (; e < nb; ++e) {
            int s = colidx[i + e];
            float w = __shfl(wA, (e << 2) + headB);
            u32 hv = *(const u32*)&h1b[(s << 7) + c];
            accx = fmaf(w, bf2f((u16)hv), accx);
            accy = fmaf(w, bf2f((u16)(hv >> 16)), accy);
            den += w;
        }
    }

    const float inv = 1.f / den;
    const float2 bv = *(const float2*)&b1[c];
    const float x2a = eluf(fmaf(accx, inv, bv.x));
    const float x2c = eluf(fmaf(accy, inv, bv.y));

    u32 pk = ((u32)f2bf(x2c) << 16) | (u32)f2bf(x2a);
    *(u32*)&x2b[(d << 7) + c] = pk;

    const float2 uv = *(const float2*)&u[c];
    const float2 vv = *(const float2*)&v[c];
    float sA = fmaf(x2a, uv.x, x2c * uv.y);
    float sB = fmaf(x2a, vv.x, x2c * vv.y);
    #pragma unroll
    for (int m = 1; m < 64; m <<= 1) {
        sA += __shfl_xor(sA, m);
        sB += __shfl_xor(sB, m);
    }
    if (lane == 0) { as2[d] = sA; ad2[d] = sB; }
}

// ---------------- KH2: h2 = x2 @ W2 via MFMA (bf16 out) --------------------
__global__ __launch_bounds__(256) void kh2(
    const u16* __restrict__ x2b, const u16* __restrict__ w2tb,
    u16* __restrict__ h2b, int N)
{
    const int wv = threadIdx.x >> 6, lane = threadIdx.x & 63;
    const int n0 = blockIdx.x * 64 + wv * 16;
    if (n0 >= N) return;
    const int m = lane & 15;
    const int kq = lane >> 4;
    bf16x8 bfr[4];
    #pragma unroll
    for (int q = 0; q < 4; ++q)
        bfr[q] = *(const bf16x8*)&w2tb[m * 128 + q * 32 + kq * 8];

    int ar = n0 + m;
    if (ar >= N) ar = N - 1;
    const u16* arow = &x2b[((size_t)ar << 7) + kq * 8];
    f32x4 acc = {0.f, 0.f, 0.f, 0.f};
    #pragma unroll
    for (int q = 0; q < 4; ++q) {
        bf16x8 af = *(const bf16x8*)&arow[q * 32];
        acc = __builtin_amdgcn_mfma_f32_16x16x32_bf16(af, bfr[q], acc, 0, 0, 0);
    }
    #pragma unroll
    for (int r = 0; r < 4; ++r) {
        int rr = n0 + kq * 4 + r;
        if (rr < N) h2b[((size_t)rr << 4) + m] = f2bf(acc[r]);
    }
}

// ---------------- KG2: layer-2 gather, in-wave weights ---------------------
__global__ __launch_bounds__(256) void kg2(
    const int* __restrict__ rowptr, const int* __restrict__ bsum,
    const int* __restrict__ colidx,
    const u16* __restrict__ h2b, const float* __restrict__ as2,
    const float* __restrict__ ad2, const float* __restrict__ b2,
    float* __restrict__ out, int N, int E)
{
    const int d = blockIdx.x * 4 + (threadIdx.x >> 6);
    if (d >= N) return;
    const int lane = threadIdx.x & 63;
    const int ch = lane & 7, g = lane >> 3;

    const float ad_d = ad2[d];
    float acc0 = 0.f, acc1 = 0.f, den = 0.f;
    int i0r = rowptr[d] + bsum[d >> 10];
    int i1r = (d + 1 == N) ? E : rowptr[d + 1] + bsum[(d + 1) >> 10];
    const int i0 = __builtin_amdgcn_readfirstlane(i0r);
    const int i1 = __builtin_amdgcn_readfirstlane(i1r);

    for (int i = i0; i < i1; i += 64) {
        const int nb = min(64, i1 - i);
        const int idx = i + lane;
        const int idxc = idx < i1 ? idx : i0;
        int sA = colidx[idxc];
        float wA = expleaky(as2[sA] + ad_d);
        wA = (idx < i1) ? wA : 0.f;
        const int kU = (nb + 7) >> 3;
        for (int k = 0; k < kU; ++k) {
            int e = g + 8 * k;
            int ec = e < nb ? e : 0;
            float w = __shfl(wA, ec);
            int s = __shfl(sA, ec);
            if (e >= nb) w = 0.f;
            u32 hv = *(const u32*)&h2b[(s << 4) + ch * 2];
            acc0 = fmaf(w, bf2f((u16)hv), acc0);
            acc1 = fmaf(w, bf2f((u16)(hv >> 16)), acc1);
            den += w;
        }
    }
    acc0 += __shfl_xor(acc0, 8); acc0 += __shfl_xor(acc0, 16); acc0 += __shfl_xor(acc0, 32);
    acc1 += __shfl_xor(acc1, 8); acc1 += __shfl_xor(acc1, 16); acc1 += __shfl_xor(acc1, 32);
    den  += __shfl_xor(den, 8);  den  += __shfl_xor(den, 16);  den  += __shfl_xor(den, 32);

    const float wself = expleaky(as2[d] + ad_d);
    u32 hd = *(const u32*)&h2b[(d << 4) + ch * 2];
    acc0 = fmaf(wself, bf2f((u16)hd), acc0);
    acc1 = fmaf(wself, bf2f((u16)(hd >> 16)), acc1);
    den += wself;
    if (g == 0) {
        float2 ov = {acc0 / den + b2[ch * 2], acc1 / den + b2[ch * 2 + 1]};
        *(float2*)&out[(d << 4) + ch * 2] = ov;
    }
}

extern "C" void kernel_launch(void* const* d_in, const int* in_sizes, int n_in,
                              void* d_out, int out_size, void* d_ws, size_t ws_size,
                              hipStream_t stream) {
    const float* x    = (const float*)d_in[0];
    const int*   ei   = (const int*)d_in[1];
    const float* W1   = (const float*)d_in[2];
    const float* ats1 = (const float*)d_in[3];
    const float* atd1 = (const float*)d_in[4];
    const float* b1   = (const float*)d_in[5];
    const float* W2   = (const float*)d_in[6];
    const float* ats2 = (const float*)d_in[7];
    const float* atd2 = (const float*)d_in[8];
    const float* b2   = (const float*)d_in[9];
    float* out = (float*)d_out;
    const int N = in_sizes[0] / 128;
    const int E = in_sizes[1] / 2;

    u16* h1b   = (u16*)d_ws;                        // 128N
    u16* x2b   = h1b + (size_t)N * 128;             // 128N
    u16* h2b   = x2b + (size_t)N * 128;             // 16N
    u16* w2tb  = h2b + (size_t)N * 16;              // 2048
    u16* w1fh  = w2tb + 2048;                       // 16384
    u16* w1fl  = w1fh + 16384;                      // 16384
    float* as1 = (float*)(w1fl + 16384);            // 4N
    float* ad1 = as1 + (size_t)N * 4;               // 4N
    float* as2 = ad1 + (size_t)N * 4;               // N
    float* ad2 = as2 + N;                           // N
    float* u   = ad2 + N;                           // 128
    float* v   = u + 128;                           // 128
    int* deg    = (int*)(v + 128);                  // N (padded)
    int* rowptr = deg + ((N + 7) & ~3);             // N+1 (padded)
    int* bsum   = rowptr + ((N + 7) & ~3);          // 128
    int* colidx = bsum + 128;                       // E
    int* rank   = colidx + E;                       // E

    const int NB = (N + 1023) / 1024;
    const int KB = (E + 2047) / 2048;               // khist blocks
    const int ntile = (N + 15) / 16;                // 6250
    const int GB = (ntile + 3) / 4;                 // kgemm blocks (4 tiles each)

    hipLaunchKernelGGL(ksetup, dim3(65 + NB), dim3(256), 0, stream,
                       W1, W2, ats2, atd2, w1fh, w1fl, u, v, w2tb, deg, N);
    hipLaunchKernelGGL(khist, dim3(KB), dim3(256), 0, stream,
                       ei, deg, rank, E);
    hipLaunchKernelGGL(kgemm, dim3(GB), dim3(256), 0, stream,
                       x, w1fh, w1fl, ats1, atd1, h1b, as1, ad1, N, GB);
    hipLaunchKernelGGL(kscan1, dim3(NB), dim3(256), 0, stream,
                       deg, rowptr, bsum, N);
    hipLaunchKernelGGL(kscan2, dim3(1), dim3(128), 0, stream, bsum, NB);
    hipLaunchKernelGGL(kscat, dim3((E + 255) / 256), dim3(256), 0, stream,
                       ei, rowptr, bsum, rank, colidx, E);
    hipLaunchKernelGGL(kg1, dim3((N + 3) / 4), dim3(256), 0, stream,
                       rowptr, bsum, colidx, h1b, as1, ad1, b1, u, v,
                       x2b, as2, ad2, N, E);
    hipLaunchKernelGGL(kh2, dim3((N + 63) / 64), dim3(256), 0, stream,
                       x2b, w2tb, h2b, N);
    hipLaunchKernelGGL(kg2, dim3((N + 3) / 4), dim3(256), 0, stream,
                       rowptr, bsum, colidx, h2b, as2, ad2, b2, out, N, E);
}

// Round 6
// 305.492 us; speedup vs baseline: 1.2626x; 1.1965x over previous
//
#include <hip/hip_runtime.h>
#include <hip/hip_bf16.h>
#include <math.h>

// GAT 2-layer. Round 15: atomic-free CSR build. R14's ablation measured the
// 1.6M scattered device atomics (khist ~75us) + scattered colidx writes
// (kscat ~60us) as throughput-bound at the ~3TB/s random-line fabric
// ceiling (~9 atomics/cycle device-wide). Replaced khist/kscan/kscat with a
// two-level bucket pipeline (kcnt -> kofs -> kbase -> kbkt2 -> kcsr): LDS
// histograms + per-bucket scans; all global writes are clustered runs, zero
// global atomics. kg1/kg2 use absolute rowptr. kgemm standalone with pinned
// B-fragments. ebuf aliases x2b (dead until kg1).

typedef unsigned short u16;
typedef unsigned int u32;
typedef __attribute__((ext_vector_type(8))) short bf16x8;
typedef __attribute__((ext_vector_type(4))) float f32x4;

__device__ __forceinline__ float eluf(float v) { return v > 0.f ? v : expm1f(v); }
__device__ __forceinline__ u16 f2bf(float f) {
    u32 u = __float_as_uint(f);
    u += 0x7fff + ((u >> 16) & 1);          // RNE
    return (u16)(u >> 16);
}
__device__ __forceinline__ float bf2f(u16 u) {
    return __uint_as_float(((u32)u) << 16);
}
// exp(leaky02(e)) = exp2(e * (e>=0 ? log2e : 0.2*log2e))
__device__ __forceinline__ float expleaky(float e) {
    float m = e >= 0.f ? 1.44269504f : 0.28853901f;
    return exp2f(e * m);
}

// ---------------- ksetup: W1 frag swizzle | W2 prep ------------------------
__global__ __launch_bounds__(256) void ksetup(
    const float* __restrict__ W1, const float* __restrict__ W2,
    const float* __restrict__ ats2, const float* __restrict__ atd2,
    u16* __restrict__ w1fh, u16* __restrict__ w1fl,
    float* __restrict__ u, float* __restrict__ v, u16* __restrict__ w2tb)
{
    const int b = blockIdx.x, tid = threadIdx.x;
    if (b < 64) {
        int idx = b * 256 + tid;
        int j = idx & 7, l = (idx >> 3) & 63, q = (idx >> 9) & 3, ct = idx >> 11;
        int k = q * 32 + (l >> 4) * 8 + j;
        int n = ct * 16 + (l & 15);
        float w = W1[k * 128 + n];
        u16 hv = f2bf(w);
        w1fh[idx] = hv;
        w1fl[idx] = f2bf(w - bf2f(hv));
    } else {
        if (tid < 128) {
            float su = 0.f, sv = 0.f;
            #pragma unroll
            for (int j = 0; j < 16; ++j) {
                float w = W2[tid * 16 + j];
                su = fmaf(w, ats2[j], su);
                sv = fmaf(w, atd2[j], sv);
                w2tb[j * 128 + tid] = f2bf(w);
            }
            u[tid] = su; v[tid] = sv;
        }
    }
}

// ---------------- kcnt: per-block bucket histogram -------------------------
// bucket = dst >> 9 (512 nodes/bucket). M[bkt*NEB + blk] = count.
__global__ __launch_bounds__(256) void kcnt(
    const int* __restrict__ ei, int* __restrict__ M,
    int E, int NEB, int NBKT)
{
    __shared__ int cnt[256];
    const int b = blockIdx.x, t = threadIdx.x;
    cnt[t] = 0;
    __syncthreads();
    const int e0 = b * 2048 + t;
    int dd[8];
    #pragma unroll
    for (int k = 0; k < 8; ++k) {
        int e = e0 + 256 * k;
        dd[k] = (e < E) ? ei[E + e] : -1;
    }
    #pragma unroll
    for (int k = 0; k < 8; ++k)
        if (dd[k] >= 0) atomicAdd(&cnt[dd[k] >> 9], 1);
    __syncthreads();
    if (t < NBKT) M[t * NEB + b] = cnt[t];
}

// ---------------- kofs: per-bucket exclusive scan over blocks --------------
__global__ __launch_bounds__(256) void kofs(
    int* __restrict__ M, int* __restrict__ tot, int NEB)
{
    __shared__ int lds[256];
    const int bkt = blockIdx.x, t = threadIdx.x;
    int carry = 0;
    const int rounds = (NEB + 255) / 256;
    for (int r = 0; r < rounds; ++r) {
        int idx = r * 256 + t;
        int v = (idx < NEB) ? M[bkt * NEB + idx] : 0;
        lds[t] = v;
        __syncthreads();
        for (int off = 1; off < 256; off <<= 1) {
            int y = (t >= off) ? lds[t - off] : 0;
            __syncthreads();
            lds[t] += y;
            __syncthreads();
        }
        if (idx < NEB) M[bkt * NEB + idx] = carry + lds[t] - v;
        carry += lds[255];
        __syncthreads();
    }
    if (t == 0) tot[bkt] = carry;
}

// ---------------- kbase: scan bucket totals -> base; rowptr[N]=E -----------
__global__ __launch_bounds__(256) void kbase(
    const int* __restrict__ tot, int* __restrict__ base,
    int* __restrict__ rowptr, int NBKT, int N, int E)
{
    __shared__ int lds[256];
    const int t = threadIdx.x;
    int v = (t < NBKT) ? tot[t] : 0;
    lds[t] = v;
    __syncthreads();
    for (int off = 1; off < 256; off <<= 1) {
        int y = (t >= off) ? lds[t - off] : 0;
        __syncthreads();
        lds[t] += y;
        __syncthreads();
    }
    if (t < NBKT) base[t] = lds[t] - v;
    if (t == 0) { base[NBKT] = E; rowptr[N] = E; }
}

// ---------------- kbkt2: scatter (dst,src) into bucket-ordered ebuf --------
__global__ __launch_bounds__(256) void kbkt2(
    const int* __restrict__ ei, const int* __restrict__ M,
    const int* __restrict__ base, uint2* __restrict__ ebuf,
    int E, int NEB, int NBKT)
{
    __shared__ int boff[256];
    __shared__ int cur[256];
    const int b = blockIdx.x, t = threadIdx.x;
    if (t < NBKT) boff[t] = base[t] + M[t * NEB + b];
    cur[t] = 0;
    __syncthreads();
    const int e0 = b * 2048 + t;
    int dd[8], ss[8];
    #pragma unroll
    for (int k = 0; k < 8; ++k) {
        int e = e0 + 256 * k;
        if (e < E) { dd[k] = ei[E + e]; ss[k] = ei[e]; } else dd[k] = -1;
    }
    #pragma unroll
    for (int k = 0; k < 8; ++k) {
        if (dd[k] >= 0) {
            int bkt = dd[k] >> 9;
            int lr = atomicAdd(&cur[bkt], 1);
            ebuf[boff[bkt] + lr] = make_uint2((u32)dd[k], (u32)ss[k]);
        }
    }
}

// ---------------- kcsr: per-bucket CSR build (LDS hist + scan + scatter) ---
__global__ __launch_bounds__(512) void kcsr(
    const uint2* __restrict__ ebuf, const int* __restrict__ base,
    int* __restrict__ rowptr, int* __restrict__ colidx, int N)
{
    __shared__ int hist[512];
    __shared__ int cur[512];
    const int k = blockIdx.x, t = threadIdx.x;
    const int e0 = base[k], e1 = base[k + 1];
    const int n0 = k << 9;
    const int nb = min(512, N - n0);
    hist[t] = 0;
    __syncthreads();
    for (int i = e0 + t; i < e1; i += 512)
        atomicAdd(&hist[ebuf[i].x & 511], 1);
    __syncthreads();
    int v = hist[t];
    // Hillis-Steele inclusive scan over 512 in-place
    for (int off = 1; off < 512; off <<= 1) {
        int y = (t >= off) ? hist[t - off] : 0;
        __syncthreads();
        hist[t] += y;
        __syncthreads();
    }
    int excl = hist[t] - v;
    cur[t] = excl;
    if (t < nb) rowptr[n0 + t] = e0 + excl;
    __syncthreads();
    for (int i = e0 + t; i < e1; i += 512) {
        uint2 es = ebuf[i];
        int r = atomicAdd(&cur[es.x & 511], 1);
        colidx[e0 + r] = (int)es.y;
    }
}

// ---------------- kgemm: persistent GEMM, pinned B-fragments ---------------
#define REPW 40   // u16 per repack row (80 B)
__global__ __launch_bounds__(256) void kgemm(
    const float* __restrict__ x, const u16* __restrict__ w1fh,
    const u16* __restrict__ w1fl,
    const float* __restrict__ att_s, const float* __restrict__ att_d,
    u16* __restrict__ h1b, float* __restrict__ as1, float* __restrict__ ad1,
    int N, int GB)
{
    __shared__ u16 rep[4][16 * REPW];
    const int tid = threadIdx.x;
    const int wv = tid >> 6, lane = tid & 63;
    const int m = lane & 15, quad = lane >> 4;
    const int h = wv;                        // head handled by this wave

    // --- B fragments for this head: cts {2h, 2h+1}, hi+lo ---
    bf16x8 bh[2][4], bl[2][4];
    #pragma unroll
    for (int sub = 0; sub < 2; ++sub) {
        #pragma unroll
        for (int q = 0; q < 4; ++q) {
            const int off = (((2 * h + sub) * 4 + q) * 64 + lane) * 8;
            bh[sub][q] = *(const bf16x8*)&w1fh[off];
            bl[sub][q] = *(const bf16x8*)&w1fl[off];
        }
    }
    // Pin the fragments in VGPRs across the tile loop.
    #pragma unroll
    for (int sub = 0; sub < 2; ++sub) {
        #pragma unroll
        for (int q = 0; q < 4; ++q) {
            asm volatile("" : "+v"(bh[sub][q]));
            asm volatile("" : "+v"(bl[sub][q]));
        }
    }

    const float cs0 = att_s[h * 32 + m];
    const float cs1 = att_s[h * 32 + 16 + m];
    const float cd0 = att_d[h * 32 + m];
    const float cd1 = att_d[h * 32 + 16 + m];

    u16* myrep = rep[wv];
    const int ntile = (N + 15) >> 4;

    for (int t = blockIdx.x; t < ntile; t += GB) {
        const int r0 = t << 4;
        int arow = r0 + m;
        if (arow >= N) arow = N - 1;
        const float* xr = &x[(size_t)arow * 128 + quad * 8];

        bf16x8 ah[4], al[4];
        #pragma unroll
        for (int q = 0; q < 4; ++q) {
            float4 f0 = *(const float4*)&xr[q * 32];
            float4 f1 = *(const float4*)&xr[q * 32 + 4];
            float fv[8] = {f0.x, f0.y, f0.z, f0.w, f1.x, f1.y, f1.z, f1.w};
            union { u16 us[8]; bf16x8 v; } hh, lu;
            #pragma unroll
            for (int j = 0; j < 8; ++j) {
                u16 hvv = f2bf(fv[j]);
                hh.us[j] = hvv;
                lu.us[j] = f2bf(fv[j] - bf2f(hvv));
            }
            ah[q] = hh.v; al[q] = lu.v;
        }

        f32x4 acc[2];
        #pragma unroll
        for (int sub = 0; sub < 2; ++sub) {
            f32x4 a = {0.f, 0.f, 0.f, 0.f};
            #pragma unroll
            for (int q = 0; q < 4; ++q) {
                a = __builtin_amdgcn_mfma_f32_16x16x32_bf16(ah[q], bh[sub][q], a, 0, 0, 0);
                a = __builtin_amdgcn_mfma_f32_16x16x32_bf16(al[q], bh[sub][q], a, 0, 0, 0);
                a = __builtin_amdgcn_mfma_f32_16x16x32_bf16(ah[q], bl[sub][q], a, 0, 0, 0);
            }
            acc[sub] = a;
        }

        float sp[4], dp[4];
        #pragma unroll
        for (int r = 0; r < 4; ++r) {
            sp[r] = fmaf(acc[0][r], cs0, acc[1][r] * cs1);
            dp[r] = fmaf(acc[0][r], cd0, acc[1][r] * cd1);
        }
        #pragma unroll
        for (int r = 0; r < 4; ++r) {
            sp[r] += __shfl_xor(sp[r], 1); sp[r] += __shfl_xor(sp[r], 2);
            sp[r] += __shfl_xor(sp[r], 4); sp[r] += __shfl_xor(sp[r], 8);
            dp[r] += __shfl_xor(dp[r], 1); dp[r] += __shfl_xor(dp[r], 2);
            dp[r] += __shfl_xor(dp[r], 4); dp[r] += __shfl_xor(dp[r], 8);
        }
        if (m == 0) {
            #pragma unroll
            for (int r = 0; r < 4; ++r) {
                int rr = r0 + quad * 4 + r;
                if (rr < N) {
                    as1[rr * 4 + h] = sp[r];
                    ad1[rr * 4 + h] = dp[r];
                }
            }
        }

        // repack -> coalesced h1b stores; wave-synchronous LDS slice.
        #pragma unroll
        for (int sub = 0; sub < 2; ++sub) {
            #pragma unroll
            for (int r = 0; r < 4; ++r)
                myrep[(quad * 4 + r) * REPW + sub * 16 + m] = f2bf(acc[sub][r]);
        }
        __asm__ __volatile__("s_waitcnt lgkmcnt(0)" ::: "memory");
        __builtin_amdgcn_sched_barrier(0);
        const int rr = lane >> 2, cc = lane & 3;
        uint4 vv = *(const uint4*)&myrep[rr * REPW + cc * 8];
        const int grow = r0 + rr;
        if (grow < N)
            *(uint4*)&h1b[(size_t)grow * 128 + h * 32 + cc * 8] = vv;
    }
}

// ---------------- KG1: layer-1 gather, in-wave weights ---------------------
__global__ __launch_bounds__(256) void kg1(
    const int* __restrict__ rowptr, const int* __restrict__ colidx,
    const u16* __restrict__ h1b, const float* __restrict__ as1,
    const float* __restrict__ ad1, const float* __restrict__ b1,
    const float* __restrict__ u, const float* __restrict__ v,
    u16* __restrict__ x2b, float* __restrict__ as2, float* __restrict__ ad2,
    int N, int E)
{
    const int d = blockIdx.x * 4 + (threadIdx.x >> 6);
    if (d >= N) return;
    const int lane = threadIdx.x & 63;
    const int c = lane * 2;
    const int headB = lane >> 4;
    const int headA = lane & 3;
    const int eA = lane >> 2;

    const float adA = ad1[d * 4 + headA];
    const float wself = expleaky(as1[d * 4 + headB] + ad1[d * 4 + headB]);
    u32 hd = *(const u32*)&h1b[(d << 7) + c];
    float accx = wself * bf2f((u16)hd);
    float accy = wself * bf2f((u16)(hd >> 16));
    float den = wself;

    int i0r = rowptr[d];
    int i1r = rowptr[d + 1];
    const int i0 = __builtin_amdgcn_readfirstlane(i0r);
    const int i1 = __builtin_amdgcn_readfirstlane(i1r);

    for (int i = i0; i < i1; i += 16) {
        const int nb = min(16, i1 - i);
        const int ii = i + eA;
        const int iic = ii < i1 ? ii : i0;
        int sAv = colidx[iic];
        float wA = expleaky(as1[(sAv << 2) + headA] + adA);
        wA = (ii < i1) ? wA : 0.f;
        int e = 0;
        for (; e + 8 <= nb; e += 8) {
            int s0 = colidx[i + e + 0];
            int s1 = colidx[i + e + 1];
            int s2 = colidx[i + e + 2];
            int s3 = colidx[i + e + 3];
            int s4 = colidx[i + e + 4];
            int s5 = colidx[i + e + 5];
            int s6 = colidx[i + e + 6];
            int s7 = colidx[i + e + 7];
            float w0 = __shfl(wA, ((e + 0) << 2) + headB);
            float w1 = __shfl(wA, ((e + 1) << 2) + headB);
            float w2 = __shfl(wA, ((e + 2) << 2) + headB);
            float w3 = __shfl(wA, ((e + 3) << 2) + headB);
            float w4 = __shfl(wA, ((e + 4) << 2) + headB);
            float w5 = __shfl(wA, ((e + 5) << 2) + headB);
            float w6 = __shfl(wA, ((e + 6) << 2) + headB);
            float w7 = __shfl(wA, ((e + 7) << 2) + headB);
            u32 v0 = *(const u32*)&h1b[(s0 << 7) + c];
            u32 v1 = *(const u32*)&h1b[(s1 << 7) + c];
            u32 v2 = *(const u32*)&h1b[(s2 << 7) + c];
            u32 v3 = *(const u32*)&h1b[(s3 << 7) + c];
            u32 v4 = *(const u32*)&h1b[(s4 << 7) + c];
            u32 v5 = *(const u32*)&h1b[(s5 << 7) + c];
            u32 v6 = *(const u32*)&h1b[(s6 << 7) + c];
            u32 v7 = *(const u32*)&h1b[(s7 << 7) + c];
            accx = fmaf(w0, bf2f((u16)v0), accx); accy = fmaf(w0, bf2f((u16)(v0 >> 16)), accy);
            accx = fmaf(w1, bf2f((u16)v1), accx); accy = fmaf(w1, bf2f((u16)(v1 >> 16)), accy);
            accx = fmaf(w2, bf2f((u16)v2), accx); accy = fmaf(w2, bf2f((u16)(v2 >> 16)), accy);
            accx = fmaf(w3, bf2f((u16)v3), accx); accy = fmaf(w3, bf2f((u16)(v3 >> 16)), accy);
            accx = fmaf(w4, bf2f((u16)v4), accx); accy = fmaf(w4, bf2f((u16)(v4 >> 16)), accy);
            accx = fmaf(w5, bf2f((u16)v5), accx); accy = fmaf(w5, bf2f((u16)(v5 >> 16)), accy);
            accx = fmaf(w6, bf2f((u16)v6), accx); accy = fmaf(w6, bf2f((u16)(v6 >> 16)), accy);
            accx = fmaf(w7, bf2f((u16)v7), accx); accy = fmaf(w7, bf2f((u16)(v7 >> 16)), accy);
            den += ((w0 + w1) + (w2 + w3)) + ((w4 + w5) + (w6 + w7));
        }
        for (; e < nb; ++e) {
            int s = colidx[i + e];
            float w = __shfl(wA, (e << 2) + headB);
            u32 hv = *(const u32*)&h1b[(s << 7) + c];
            accx = fmaf(w, bf2f((u16)hv), accx);
            accy = fmaf(w, bf2f((u16)(hv >> 16)), accy);
            den += w;
        }
    }

    const float inv = 1.f / den;
    const float2 bv = *(const float2*)&b1[c];
    const float x2a = eluf(fmaf(accx, inv, bv.x));
    const float x2c = eluf(fmaf(accy, inv, bv.y));

    u32 pk = ((u32)f2bf(x2c) << 16) | (u32)f2bf(x2a);
    *(u32*)&x2b[(d << 7) + c] = pk;

    const float2 uv = *(const float2*)&u[c];
    const float2 vv = *(const float2*)&v[c];
    float sA = fmaf(x2a, uv.x, x2c * uv.y);
    float sB = fmaf(x2a, vv.x, x2c * vv.y);
    #pragma unroll
    for (int m = 1; m < 64; m <<= 1) {
        sA += __shfl_xor(sA, m);
        sB += __shfl_xor(sB, m);
    }
    if (lane == 0) { as2[d] = sA; ad2[d] = sB; }
}

// ---------------- KH2: h2 = x2 @ W2 via MFMA (bf16 out) --------------------
__global__ __launch_bounds__(256) void kh2(
    const u16* __restrict__ x2b, const u16* __restrict__ w2tb,
    u16* __restrict__ h2b, int N)
{
    const int wv = threadIdx.x >> 6, lane = threadIdx.x & 63;
    const int n0 = blockIdx.x * 64 + wv * 16;
    if (n0 >= N) return;
    const int m = lane & 15;
    const int kq = lane >> 4;
    bf16x8 bfr[4];
    #pragma unroll
    for (int q = 0; q < 4; ++q)
        bfr[q] = *(const bf16x8*)&w2tb[m * 128 + q * 32 + kq * 8];

    int ar = n0 + m;
    if (ar >= N) ar = N - 1;
    const u16* arow = &x2b[((size_t)ar << 7) + kq * 8];
    f32x4 acc = {0.f, 0.f, 0.f, 0.f};
    #pragma unroll
    for (int q = 0; q < 4; ++q) {
        bf16x8 af = *(const bf16x8*)&arow[q * 32];
        acc = __builtin_amdgcn_mfma_f32_16x16x32_bf16(af, bfr[q], acc, 0, 0, 0);
    }
    #pragma unroll
    for (int r = 0; r < 4; ++r) {
        int rr = n0 + kq * 4 + r;
        if (rr < N) h2b[((size_t)rr << 4) + m] = f2bf(acc[r]);
    }
}

// ---------------- KG2: layer-2 gather, in-wave weights ---------------------
__global__ __launch_bounds__(256) void kg2(
    const int* __restrict__ rowptr, const int* __restrict__ colidx,
    const u16* __restrict__ h2b, const float* __restrict__ as2,
    const float* __restrict__ ad2, const float* __restrict__ b2,
    float* __restrict__ out, int N, int E)
{
    const int d = blockIdx.x * 4 + (threadIdx.x >> 6);
    if (d >= N) return;
    const int lane = threadIdx.x & 63;
    const int ch = lane & 7, g = lane >> 3;

    const float ad_d = ad2[d];
    float acc0 = 0.f, acc1 = 0.f, den = 0.f;
    int i0r = rowptr[d];
    int i1r = rowptr[d + 1];
    const int i0 = __builtin_amdgcn_readfirstlane(i0r);
    const int i1 = __builtin_amdgcn_readfirstlane(i1r);

    for (int i = i0; i < i1; i += 64) {
        const int nb = min(64, i1 - i);
        const int idx = i + lane;
        const int idxc = idx < i1 ? idx : i0;
        int sA = colidx[idxc];
        float wA = expleaky(as2[sA] + ad_d);
        wA = (idx < i1) ? wA : 0.f;
        const int kU = (nb + 7) >> 3;
        for (int k = 0; k < kU; ++k) {
            int e = g + 8 * k;
            int ec = e < nb ? e : 0;
            float w = __shfl(wA, ec);
            int s = __shfl(sA, ec);
            if (e >= nb) w = 0.f;
            u32 hv = *(const u32*)&h2b[(s << 4) + ch * 2];
            acc0 = fmaf(w, bf2f((u16)hv), acc0);
            acc1 = fmaf(w, bf2f((u16)(hv >> 16)), acc1);
            den += w;
        }
    }
    acc0 += __shfl_xor(acc0, 8); acc0 += __shfl_xor(acc0, 16); acc0 += __shfl_xor(acc0, 32);
    acc1 += __shfl_xor(acc1, 8); acc1 += __shfl_xor(acc1, 16); acc1 += __shfl_xor(acc1, 32);
    den  += __shfl_xor(den, 8);  den  += __shfl_xor(den, 16);  den  += __shfl_xor(den, 32);

    const float wself = expleaky(as2[d] + ad_d);
    u32 hd = *(const u32*)&h2b[(d << 4) + ch * 2];
    acc0 = fmaf(wself, bf2f((u16)hd), acc0);
    acc1 = fmaf(wself, bf2f((u16)(hd >> 16)), acc1);
    den += wself;
    if (g == 0) {
        float2 ov = {acc0 / den + b2[ch * 2], acc1 / den + b2[ch * 2 + 1]};
        *(float2*)&out[(d << 4) + ch * 2] = ov;
    }
}

extern "C" void kernel_launch(void* const* d_in, const int* in_sizes, int n_in,
                              void* d_out, int out_size, void* d_ws, size_t ws_size,
                              hipStream_t stream) {
    const float* x    = (const float*)d_in[0];
    const int*   ei   = (const int*)d_in[1];
    const float* W1   = (const float*)d_in[2];
    const float* ats1 = (const float*)d_in[3];
    const float* atd1 = (const float*)d_in[4];
    const float* b1   = (const float*)d_in[5];
    const float* W2   = (const float*)d_in[6];
    const float* ats2 = (const float*)d_in[7];
    const float* atd2 = (const float*)d_in[8];
    const float* b2   = (const float*)d_in[9];
    float* out = (float*)d_out;
    const int N = in_sizes[0] / 128;
    const int E = in_sizes[1] / 2;

    const int NEB  = (E + 2047) / 2048;             // edge blocks (782)
    const int NBKT = (N + 511) >> 9;                // node buckets (196)

    u16* h1b   = (u16*)d_ws;                        // 128N
    u16* x2b   = h1b + (size_t)N * 128;             // 128N (ebuf aliases)
    u16* h2b   = x2b + (size_t)N * 128;             // 16N
    u16* w2tb  = h2b + (size_t)N * 16;              // 2048
    u16* w1fh  = w2tb + 2048;                       // 16384
    u16* w1fl  = w1fh + 16384;                      // 16384
    float* as1 = (float*)(w1fl + 16384);            // 4N
    float* ad1 = as1 + (size_t)N * 4;               // 4N
    float* as2 = ad1 + (size_t)N * 4;               // N
    float* ad2 = as2 + N;                           // N
    float* u   = ad2 + N;                           // 128
    float* v   = u + 128;                           // 128
    int* rowptr = (int*)(v + 128);                  // N+1 (padded)
    int* colidx = rowptr + ((N + 8) & ~3);          // E
    int* M      = colidx + E;                       // NBKT*NEB
    int* tot    = M + (size_t)NBKT * NEB;           // NBKT
    int* base   = tot + NBKT;                       // NBKT+1
    uint2* ebuf = (uint2*)x2b;                      // E pairs (dead until kg1)

    const int ntile = (N + 15) / 16;
    const int GB = (ntile + 3) / 4;                 // kgemm blocks (4 tiles each)

    hipLaunchKernelGGL(ksetup, dim3(65), dim3(256), 0, stream,
                       W1, W2, ats2, atd2, w1fh, w1fl, u, v, w2tb);
    hipLaunchKernelGGL(kgemm, dim3(GB), dim3(256), 0, stream,
                       x, w1fh, w1fl, ats1, atd1, h1b, as1, ad1, N, GB);
    hipLaunchKernelGGL(kcnt, dim3(NEB), dim3(256), 0, stream,
                       ei, M, E, NEB, NBKT);
    hipLaunchKernelGGL(kofs, dim3(NBKT), dim3(256), 0, stream, M, tot, NEB);
    hipLaunchKernelGGL(kbase, dim3(1), dim3(256), 0, stream,
                       tot, base, rowptr, NBKT, N, E);
    hipLaunchKernelGGL(kbkt2, dim3(NEB), dim3(256), 0, stream,
                       ei, M, base, ebuf, E, NEB, NBKT);
    hipLaunchKernelGGL(kcsr, dim3(NBKT), dim3(512), 0, stream,
                       ebuf, base, rowptr, colidx, N);
    hipLaunchKernelGGL(kg1, dim3((N + 3) / 4), dim3(256), 0, stream,
                       rowptr, colidx, h1b, as1, ad1, b1, u, v,
                       x2b, as2, ad2, N, E);
    hipLaunchKernelGGL(kh2, dim3((N + 63) / 64), dim3(256), 0, stream,
                       x2b, w2tb, h2b, N);
    hipLaunchKernelGGL(kg2, dim3((N + 3) / 4), dim3(256), 0, stream,
                       rowptr, colidx, h2b, as2, ad2, b2, out, N, E);
}

// Round 7
// 298.818 us; speedup vs baseline: 1.2908x; 1.0223x over previous
//
#include <hip/hip_runtime.h>
#include <hip/hip_bf16.h>
#include <math.h>

// GAT 2-layer. Round 16: LDS-staged scatters in the CSR chain. R15's kbkt2
// and kcsr did 64-distinct-line wave-stores (transaction-count-bound even
// when L2-resident). v2 sorts into LDS first, then streams out: kbkt2 stages
// (dst,src)+global-pos in LDS so the write loop emits ~6 consecutive runs
// per wave instead of 64 scattered lines; kcsr stages colidx in LDS (8832
// cap, overflow-guarded) and streams it out coalesced. Everything else
// byte-identical to R15 (kg1 is at the ~3.2 TB/s random-gather fabric
// ceiling; 240 MB FETCH, floor ~75us).

typedef unsigned short u16;
typedef unsigned int u32;
typedef __attribute__((ext_vector_type(8))) short bf16x8;
typedef __attribute__((ext_vector_type(4))) float f32x4;

__device__ __forceinline__ float eluf(float v) { return v > 0.f ? v : expm1f(v); }
__device__ __forceinline__ u16 f2bf(float f) {
    u32 u = __float_as_uint(f);
    u += 0x7fff + ((u >> 16) & 1);          // RNE
    return (u16)(u >> 16);
}
__device__ __forceinline__ float bf2f(u16 u) {
    return __uint_as_float(((u32)u) << 16);
}
// exp(leaky02(e)) = exp2(e * (e>=0 ? log2e : 0.2*log2e))
__device__ __forceinline__ float expleaky(float e) {
    float m = e >= 0.f ? 1.44269504f : 0.28853901f;
    return exp2f(e * m);
}

// ---------------- ksetup: W1 frag swizzle | W2 prep ------------------------
__global__ __launch_bounds__(256) void ksetup(
    const float* __restrict__ W1, const float* __restrict__ W2,
    const float* __restrict__ ats2, const float* __restrict__ atd2,
    u16* __restrict__ w1fh, u16* __restrict__ w1fl,
    float* __restrict__ u, float* __restrict__ v, u16* __restrict__ w2tb)
{
    const int b = blockIdx.x, tid = threadIdx.x;
    if (b < 64) {
        int idx = b * 256 + tid;
        int j = idx & 7, l = (idx >> 3) & 63, q = (idx >> 9) & 3, ct = idx >> 11;
        int k = q * 32 + (l >> 4) * 8 + j;
        int n = ct * 16 + (l & 15);
        float w = W1[k * 128 + n];
        u16 hv = f2bf(w);
        w1fh[idx] = hv;
        w1fl[idx] = f2bf(w - bf2f(hv));
    } else {
        if (tid < 128) {
            float su = 0.f, sv = 0.f;
            #pragma unroll
            for (int j = 0; j < 16; ++j) {
                float w = W2[tid * 16 + j];
                su = fmaf(w, ats2[j], su);
                sv = fmaf(w, atd2[j], sv);
                w2tb[j * 128 + tid] = f2bf(w);
            }
            u[tid] = su; v[tid] = sv;
        }
    }
}

// ---------------- kcnt: per-block bucket histogram -------------------------
// bucket = dst >> 9 (512 nodes/bucket). M[bkt*NEB + blk] = count.
__global__ __launch_bounds__(256) void kcnt(
    const int* __restrict__ ei, int* __restrict__ M,
    int E, int NEB, int NBKT)
{
    __shared__ int cnt[256];
    const int b = blockIdx.x, t = threadIdx.x;
    cnt[t] = 0;
    __syncthreads();
    const int e0 = b * 2048 + t;
    int dd[8];
    #pragma unroll
    for (int k = 0; k < 8; ++k) {
        int e = e0 + 256 * k;
        dd[k] = (e < E) ? ei[E + e] : -1;
    }
    #pragma unroll
    for (int k = 0; k < 8; ++k)
        if (dd[k] >= 0) atomicAdd(&cnt[dd[k] >> 9], 1);
    __syncthreads();
    if (t < NBKT) M[t * NEB + b] = cnt[t];
}

// ---------------- kofs: per-bucket exclusive scan over blocks --------------
__global__ __launch_bounds__(256) void kofs(
    int* __restrict__ M, int* __restrict__ tot, int NEB)
{
    __shared__ int lds[256];
    const int bkt = blockIdx.x, t = threadIdx.x;
    int carry = 0;
    const int rounds = (NEB + 255) / 256;
    for (int r = 0; r < rounds; ++r) {
        int idx = r * 256 + t;
        int v = (idx < NEB) ? M[bkt * NEB + idx] : 0;
        lds[t] = v;
        __syncthreads();
        for (int off = 1; off < 256; off <<= 1) {
            int y = (t >= off) ? lds[t - off] : 0;
            __syncthreads();
            lds[t] += y;
            __syncthreads();
        }
        if (idx < NEB) M[bkt * NEB + idx] = carry + lds[t] - v;
        carry += lds[255];
        __syncthreads();
    }
    if (t == 0) tot[bkt] = carry;
}

// ---------------- kbase: scan bucket totals -> base; rowptr[N]=E -----------
__global__ __launch_bounds__(256) void kbase(
    const int* __restrict__ tot, int* __restrict__ base,
    int* __restrict__ rowptr, int NBKT, int N, int E)
{
    __shared__ int lds[256];
    const int t = threadIdx.x;
    int v = (t < NBKT) ? tot[t] : 0;
    lds[t] = v;
    __syncthreads();
    for (int off = 1; off < 256; off <<= 1) {
        int y = (t >= off) ? lds[t - off] : 0;
        __syncthreads();
        lds[t] += y;
        __syncthreads();
    }
    if (t < NBKT) base[t] = lds[t] - v;
    if (t == 0) { base[NBKT] = E; rowptr[N] = E; }
}

// ---------------- kbkt2 v2: LDS-staged bucket scatter ----------------------
// Stage (dst,src) sorted-by-bucket in LDS along with each edge's global
// position, then stream out: a wave's 64 stores span ~6 consecutive runs
// instead of 64 scattered lines.
__global__ __launch_bounds__(256) void kbkt2(
    const int* __restrict__ ei, const int* __restrict__ M,
    const int* __restrict__ base, uint2* __restrict__ ebuf,
    int E, int NEB, int NBKT)
{
    __shared__ int cnt[256], lofs[256], cur[256], boff[256];
    __shared__ uint2 st[2048];
    __shared__ int gp[2048];
    const int b = blockIdx.x, t = threadIdx.x;
    cnt[t] = 0; cur[t] = 0;
    __syncthreads();
    const int e0 = b * 2048 + t;
    int dd[8], ss[8];
    #pragma unroll
    for (int k = 0; k < 8; ++k) {
        int e = e0 + 256 * k;
        if (e < E) { dd[k] = ei[E + e]; ss[k] = ei[e]; } else dd[k] = -1;
    }
    #pragma unroll
    for (int k = 0; k < 8; ++k)
        if (dd[k] >= 0) atomicAdd(&cnt[dd[k] >> 9], 1);
    if (t < NBKT) boff[t] = base[t] + M[t * NEB + b];
    __syncthreads();
    // exclusive scan of cnt -> lofs (local bucket starts within stage)
    int v = cnt[t];
    lofs[t] = v;
    __syncthreads();
    for (int off = 1; off < 256; off <<= 1) {
        int y = (t >= off) ? lofs[t - off] : 0;
        __syncthreads();
        lofs[t] += y;
        __syncthreads();
    }
    int excl = lofs[t] - v;
    __syncthreads();
    lofs[t] = excl;
    __syncthreads();
    #pragma unroll
    for (int k = 0; k < 8; ++k) {
        if (dd[k] >= 0) {
            int bkt = dd[k] >> 9;
            int lr = atomicAdd(&cur[bkt], 1);
            int pos = lofs[bkt] + lr;
            st[pos] = make_uint2((u32)dd[k], (u32)ss[k]);
            gp[pos] = boff[bkt] + lr;
        }
    }
    __syncthreads();
    const int nv = min(2048, E - b * 2048);
    for (int i = t; i < nv; i += 256)
        ebuf[gp[i]] = st[i];
}

// ---------------- kcsr v2: per-bucket CSR build, LDS-staged colidx ---------
#define CSTAGE 8832
__global__ __launch_bounds__(512) void kcsr(
    const uint2* __restrict__ ebuf, const int* __restrict__ base,
    int* __restrict__ rowptr, int* __restrict__ colidx, int N)
{
    __shared__ int hist[512];
    __shared__ int cur[512];
    __shared__ int stage[CSTAGE];
    const int k = blockIdx.x, t = threadIdx.x;
    const int e0 = base[k], e1 = base[k + 1];
    const int n0 = k << 9;
    const int nb = min(512, N - n0);
    hist[t] = 0;
    __syncthreads();
    for (int i = e0 + t; i < e1; i += 512)
        atomicAdd(&hist[ebuf[i].x & 511], 1);
    __syncthreads();
    int v = hist[t];
    // Hillis-Steele inclusive scan over 512 in-place
    for (int off = 1; off < 512; off <<= 1) {
        int y = (t >= off) ? hist[t - off] : 0;
        __syncthreads();
        hist[t] += y;
        __syncthreads();
    }
    int excl = hist[t] - v;
    cur[t] = excl;
    if (t < nb) rowptr[n0 + t] = e0 + excl;
    __syncthreads();
    for (int i = e0 + t; i < e1; i += 512) {
        uint2 es = ebuf[i];
        int r = atomicAdd(&cur[es.x & 511], 1);
        if (r < CSTAGE) stage[r] = (int)es.y;
        else colidx[e0 + r] = (int)es.y;
    }
    __syncthreads();
    const int ne = e1 - e0;
    const int lim = ne < CSTAGE ? ne : CSTAGE;
    for (int i = t; i < lim; i += 512)
        colidx[e0 + i] = stage[i];
}

// ---------------- kgemm: persistent GEMM, pinned B-fragments ---------------
#define REPW 40   // u16 per repack row (80 B)
__global__ __launch_bounds__(256) void kgemm(
    const float* __restrict__ x, const u16* __restrict__ w1fh,
    const u16* __restrict__ w1fl,
    const float* __restrict__ att_s, const float* __restrict__ att_d,
    u16* __restrict__ h1b, float* __restrict__ as1, float* __restrict__ ad1,
    int N, int GB)
{
    __shared__ u16 rep[4][16 * REPW];
    const int tid = threadIdx.x;
    const int wv = tid >> 6, lane = tid & 63;
    const int m = lane & 15, quad = lane >> 4;
    const int h = wv;                        // head handled by this wave

    // --- B fragments for this head: cts {2h, 2h+1}, hi+lo ---
    bf16x8 bh[2][4], bl[2][4];
    #pragma unroll
    for (int sub = 0; sub < 2; ++sub) {
        #pragma unroll
        for (int q = 0; q < 4; ++q) {
            const int off = (((2 * h + sub) * 4 + q) * 64 + lane) * 8;
            bh[sub][q] = *(const bf16x8*)&w1fh[off];
            bl[sub][q] = *(const bf16x8*)&w1fl[off];
        }
    }
    // Pin the fragments in VGPRs across the tile loop.
    #pragma unroll
    for (int sub = 0; sub < 2; ++sub) {
        #pragma unroll
        for (int q = 0; q < 4; ++q) {
            asm volatile("" : "+v"(bh[sub][q]));
            asm volatile("" : "+v"(bl[sub][q]));
        }
    }

    const float cs0 = att_s[h * 32 + m];
    const float cs1 = att_s[h * 32 + 16 + m];
    const float cd0 = att_d[h * 32 + m];
    const float cd1 = att_d[h * 32 + 16 + m];

    u16* myrep = rep[wv];
    const int ntile = (N + 15) >> 4;

    for (int t = blockIdx.x; t < ntile; t += GB) {
        const int r0 = t << 4;
        int arow = r0 + m;
        if (arow >= N) arow = N - 1;
        const float* xr = &x[(size_t)arow * 128 + quad * 8];

        bf16x8 ah[4], al[4];
        #pragma unroll
        for (int q = 0; q < 4; ++q) {
            float4 f0 = *(const float4*)&xr[q * 32];
            float4 f1 = *(const float4*)&xr[q * 32 + 4];
            float fv[8] = {f0.x, f0.y, f0.z, f0.w, f1.x, f1.y, f1.z, f1.w};
            union { u16 us[8]; bf16x8 v; } hh, lu;
            #pragma unroll
            for (int j = 0; j < 8; ++j) {
                u16 hvv = f2bf(fv[j]);
                hh.us[j] = hvv;
                lu.us[j] = f2bf(fv[j] - bf2f(hvv));
            }
            ah[q] = hh.v; al[q] = lu.v;
        }

        f32x4 acc[2];
        #pragma unroll
        for (int sub = 0; sub < 2; ++sub) {
            f32x4 a = {0.f, 0.f, 0.f, 0.f};
            #pragma unroll
            for (int q = 0; q < 4; ++q) {
                a = __builtin_amdgcn_mfma_f32_16x16x32_bf16(ah[q], bh[sub][q], a, 0, 0, 0);
                a = __builtin_amdgcn_mfma_f32_16x16x32_bf16(al[q], bh[sub][q], a, 0, 0, 0);
                a = __builtin_amdgcn_mfma_f32_16x16x32_bf16(ah[q], bl[sub][q], a, 0, 0, 0);
            }
            acc[sub] = a;
        }

        float sp[4], dp[4];
        #pragma unroll
        for (int r = 0; r < 4; ++r) {
            sp[r] = fmaf(acc[0][r], cs0, acc[1][r] * cs1);
            dp[r] = fmaf(acc[0][r], cd0, acc[1][r] * cd1);
        }
        #pragma unroll
        for (int r = 0; r < 4; ++r) {
            sp[r] += __shfl_xor(sp[r], 1); sp[r] += __shfl_xor(sp[r], 2);
            sp[r] += __shfl_xor(sp[r], 4); sp[r] += __shfl_xor(sp[r], 8);
            dp[r] += __shfl_xor(dp[r], 1); dp[r] += __shfl_xor(dp[r], 2);
            dp[r] += __shfl_xor(dp[r], 4); dp[r] += __shfl_xor(dp[r], 8);
        }
        if (m == 0) {
            #pragma unroll
            for (int r = 0; r < 4; ++r) {
                int rr = r0 + quad * 4 + r;
                if (rr < N) {
                    as1[rr * 4 + h] = sp[r];
                    ad1[rr * 4 + h] = dp[r];
                }
            }
        }

        // repack -> coalesced h1b stores; wave-synchronous LDS slice.
        #pragma unroll
        for (int sub = 0; sub < 2; ++sub) {
            #pragma unroll
            for (int r = 0; r < 4; ++r)
                myrep[(quad * 4 + r) * REPW + sub * 16 + m] = f2bf(acc[sub][r]);
        }
        __asm__ __volatile__("s_waitcnt lgkmcnt(0)" ::: "memory");
        __builtin_amdgcn_sched_barrier(0);
        const int rr = lane >> 2, cc = lane & 3;
        uint4 vv = *(const uint4*)&myrep[rr * REPW + cc * 8];
        const int grow = r0 + rr;
        if (grow < N)
            *(uint4*)&h1b[(size_t)grow * 128 + h * 32 + cc * 8] = vv;
    }
}

// ---------------- KG1: layer-1 gather, in-wave weights ---------------------
__global__ __launch_bounds__(256) void kg1(
    const int* __restrict__ rowptr, const int* __restrict__ colidx,
    const u16* __restrict__ h1b, const float* __restrict__ as1,
    const float* __restrict__ ad1, const float* __restrict__ b1,
    const float* __restrict__ u, const float* __restrict__ v,
    u16* __restrict__ x2b, float* __restrict__ as2, float* __restrict__ ad2,
    int N, int E)
{
    const int d = blockIdx.x * 4 + (threadIdx.x >> 6);
    if (d >= N) return;
    const int lane = threadIdx.x & 63;
    const int c = lane * 2;
    const int headB = lane >> 4;
    const int headA = lane & 3;
    const int eA = lane >> 2;

    const float adA = ad1[d * 4 + headA];
    const float wself = expleaky(as1[d * 4 + headB] + ad1[d * 4 + headB]);
    u32 hd = *(const u32*)&h1b[(d << 7) + c];
    float accx = wself * bf2f((u16)hd);
    float accy = wself * bf2f((u16)(hd >> 16));
    float den = wself;

    int i0r = rowptr[d];
    int i1r = rowptr[d + 1];
    const int i0 = __builtin_amdgcn_readfirstlane(i0r);
    const int i1 = __builtin_amdgcn_readfirstlane(i1r);

    for (int i = i0; i < i1; i += 16) {
        const int nb = min(16, i1 - i);
        const int ii = i + eA;
        const int iic = ii < i1 ? ii : i0;
        int sAv = colidx[iic];
        float wA = expleaky(as1[(sAv << 2) + headA] + adA);
        wA = (ii < i1) ? wA : 0.f;
        int e = 0;
        for (; e + 8 <= nb; e += 8) {
            int s0 = colidx[i + e + 0];
            int s1 = colidx[i + e + 1];
            int s2 = colidx[i + e + 2];
            int s3 = colidx[i + e + 3];
            int s4 = colidx[i + e + 4];
            int s5 = colidx[i + e + 5];
            int s6 = colidx[i + e + 6];
            int s7 = colidx[i + e + 7];
            float w0 = __shfl(wA, ((e + 0) << 2) + headB);
            float w1 = __shfl(wA, ((e + 1) << 2) + headB);
            float w2 = __shfl(wA, ((e + 2) << 2) + headB);
            float w3 = __shfl(wA, ((e + 3) << 2) + headB);
            float w4 = __shfl(wA, ((e + 4) << 2) + headB);
            float w5 = __shfl(wA, ((e + 5) << 2) + headB);
            float w6 = __shfl(wA, ((e + 6) << 2) + headB);
            float w7 = __shfl(wA, ((e + 7) << 2) + headB);
            u32 v0 = *(const u32*)&h1b[(s0 << 7) + c];
            u32 v1 = *(const u32*)&h1b[(s1 << 7) + c];
            u32 v2 = *(const u32*)&h1b[(s2 << 7) + c];
            u32 v3 = *(const u32*)&h1b[(s3 << 7) + c];
            u32 v4 = *(const u32*)&h1b[(s4 << 7) + c];
            u32 v5 = *(const u32*)&h1b[(s5 << 7) + c];
            u32 v6 = *(const u32*)&h1b[(s6 << 7) + c];
            u32 v7 = *(const u32*)&h1b[(s7 << 7) + c];
            accx = fmaf(w0, bf2f((u16)v0), accx); accy = fmaf(w0, bf2f((u16)(v0 >> 16)), accy);
            accx = fmaf(w1, bf2f((u16)v1), accx); accy = fmaf(w1, bf2f((u16)(v1 >> 16)), accy);
            accx = fmaf(w2, bf2f((u16)v2), accx); accy = fmaf(w2, bf2f((u16)(v2 >> 16)), accy);
            accx = fmaf(w3, bf2f((u16)v3), accx); accy = fmaf(w3, bf2f((u16)(v3 >> 16)), accy);
            accx = fmaf(w4, bf2f((u16)v4), accx); accy = fmaf(w4, bf2f((u16)(v4 >> 16)), accy);
            accx = fmaf(w5, bf2f((u16)v5), accx); accy = fmaf(w5, bf2f((u16)(v5 >> 16)), accy);
            accx = fmaf(w6, bf2f((u16)v6), accx); accy = fmaf(w6, bf2f((u16)(v6 >> 16)), accy);
            accx = fmaf(w7, bf2f((u16)v7), accx); accy = fmaf(w7, bf2f((u16)(v7 >> 16)), accy);
            den += ((w0 + w1) + (w2 + w3)) + ((w4 + w5) + (w6 + w7));
        }
        for (; e < nb; ++e) {
            int s = colidx[i + e];
            float w = __shfl(wA, (e << 2) + headB);
            u32 hv = *(const u32*)&h1b[(s << 7) + c];
            accx = fmaf(w, bf2f((u16)hv), accx);
            accy = fmaf(w, bf2f((u16)(hv >> 16)), accy);
            den += w;
        }
    }

    const float inv = 1.f / den;
    const float2 bv = *(const float2*)&b1[c];
    const float x2a = eluf(fmaf(accx, inv, bv.x));
    const float x2c = eluf(fmaf(accy, inv, bv.y));

    u32 pk = ((u32)f2bf(x2c) << 16) | (u32)f2bf(x2a);
    *(u32*)&x2b[(d << 7) + c] = pk;

    const float2 uv = *(const float2*)&u[c];
    const float2 vv = *(const float2*)&v[c];
    float sA = fmaf(x2a, uv.x, x2c * uv.y);
    float sB = fmaf(x2a, vv.x, x2c * vv.y);
    #pragma unroll
    for (int m = 1; m < 64; m <<= 1) {
        sA += __shfl_xor(sA, m);
        sB += __shfl_xor(sB, m);
    }
    if (lane == 0) { as2[d] = sA; ad2[d] = sB; }
}

// ---------------- KH2: h2 = x2 @ W2 via MFMA (bf16 out) --------------------
__global__ __launch_bounds__(256) void kh2(
    const u16* __restrict__ x2b, const u16* __restrict__ w2tb,
    u16* __restrict__ h2b, int N)
{
    const int wv = threadIdx.x >> 6, lane = threadIdx.x & 63;
    const int n0 = blockIdx.x * 64 + wv * 16;
    if (n0 >= N) return;
    const int m = lane & 15;
    const int kq = lane >> 4;
    bf16x8 bfr[4];
    #pragma unroll
    for (int q = 0; q < 4; ++q)
        bfr[q] = *(const bf16x8*)&w2tb[m * 128 + q * 32 + kq * 8];

    int ar = n0 + m;
    if (ar >= N) ar = N - 1;
    const u16* arow = &x2b[((size_t)ar << 7) + kq * 8];
    f32x4 acc = {0.f, 0.f, 0.f, 0.f};
    #pragma unroll
    for (int q = 0; q < 4; ++q) {
        bf16x8 af = *(const bf16x8*)&arow[q * 32];
        acc = __builtin_amdgcn_mfma_f32_16x16x32_bf16(af, bfr[q], acc, 0, 0, 0);
    }
    #pragma unroll
    for (int r = 0; r < 4; ++r) {
        int rr = n0 + kq * 4 + r;
        if (rr < N) h2b[((size_t)rr << 4) + m] = f2bf(acc[r]);
    }
}

// ---------------- KG2: layer-2 gather, in-wave weights ---------------------
__global__ __launch_bounds__(256) void kg2(
    const int* __restrict__ rowptr, const int* __restrict__ colidx,
    const u16* __restrict__ h2b, const float* __restrict__ as2,
    const float* __restrict__ ad2, const float* __restrict__ b2,
    float* __restrict__ out, int N, int E)
{
    const int d = blockIdx.x * 4 + (threadIdx.x >> 6);
    if (d >= N) return;
    const int lane = threadIdx.x & 63;
    const int ch = lane & 7, g = lane >> 3;

    const float ad_d = ad2[d];
    float acc0 = 0.f, acc1 = 0.f, den = 0.f;
    int i0r = rowptr[d];
    int i1r = rowptr[d + 1];
    const int i0 = __builtin_amdgcn_readfirstlane(i0r);
    const int i1 = __builtin_amdgcn_readfirstlane(i1r);

    for (int i = i0; i < i1; i += 64) {
        const int nb = min(64, i1 - i);
        const int idx = i + lane;
        const int idxc = idx < i1 ? idx : i0;
        int sA = colidx[idxc];
        float wA = expleaky(as2[sA] + ad_d);
        wA = (idx < i1) ? wA : 0.f;
        const int kU = (nb + 7) >> 3;
        for (int k = 0; k < kU; ++k) {
            int e = g + 8 * k;
            int ec = e < nb ? e : 0;
            float w = __shfl(wA, ec);
            int s = __shfl(sA, ec);
            if (e >= nb) w = 0.f;
            u32 hv = *(const u32*)&h2b[(s << 4) + ch * 2];
            acc0 = fmaf(w, bf2f((u16)hv), acc0);
            acc1 = fmaf(w, bf2f((u16)(hv >> 16)), acc1);
            den += w;
        }
    }
    acc0 += __shfl_xor(acc0, 8); acc0 += __shfl_xor(acc0, 16); acc0 += __shfl_xor(acc0, 32);
    acc1 += __shfl_xor(acc1, 8); acc1 += __shfl_xor(acc1, 16); acc1 += __shfl_xor(acc1, 32);
    den  += __shfl_xor(den, 8);  den  += __shfl_xor(den, 16);  den  += __shfl_xor(den, 32);

    const float wself = expleaky(as2[d] + ad_d);
    u32 hd = *(const u32*)&h2b[(d << 4) + ch * 2];
    acc0 = fmaf(wself, bf2f((u16)hd), acc0);
    acc1 = fmaf(wself, bf2f((u16)(hd >> 16)), acc1);
    den += wself;
    if (g == 0) {
        float2 ov = {acc0 / den + b2[ch * 2], acc1 / den + b2[ch * 2 + 1]};
        *(float2*)&out[(d << 4) + ch * 2] = ov;
    }
}

extern "C" void kernel_launch(void* const* d_in, const int* in_sizes, int n_in,
                              void* d_out, int out_size, void* d_ws, size_t ws_size,
                              hipStream_t stream) {
    const float* x    = (const float*)d_in[0];
    const int*   ei   = (const int*)d_in[1];
    const float* W1   = (const float*)d_in[2];
    const float* ats1 = (const float*)d_in[3];
    const float* atd1 = (const float*)d_in[4];
    const float* b1   = (const float*)d_in[5];
    const float* W2   = (const float*)d_in[6];
    const float* ats2 = (const float*)d_in[7];
    const float* atd2 = (const float*)d_in[8];
    const float* b2   = (const float*)d_in[9];
    float* out = (float*)d_out;
    const int N = in_sizes[0] / 128;
    const int E = in_sizes[1] / 2;

    const int NEB  = (E + 2047) / 2048;             // edge blocks (782)
    const int NBKT = (N + 511) >> 9;                // node buckets (196)

    u16* h1b   = (u16*)d_ws;                        // 128N
    u16* x2b   = h1b + (size_t)N * 128;             // 128N (ebuf aliases)
    u16* h2b   = x2b + (size_t)N * 128;             // 16N
    u16* w2tb  = h2b + (size_t)N * 16;              // 2048
    u16* w1fh  = w2tb + 2048;                       // 16384
    u16* w1fl  = w1fh + 16384;                      // 16384
    float* as1 = (float*)(w1fl + 16384);            // 4N
    float* ad1 = as1 + (size_t)N * 4;               // 4N
    float* as2 = ad1 + (size_t)N * 4;               // N
    float* ad2 = as2 + N;                           // N
    float* u   = ad2 + N;                           // 128
    float* v   = u + 128;                           // 128
    int* rowptr = (int*)(v + 128);                  // N+1 (padded)
    int* colidx = rowptr + ((N + 8) & ~3);          // E
    int* M      = colidx + E;                       // NBKT*NEB
    int* tot    = M + (size_t)NBKT * NEB;           // NBKT
    int* base   = tot + NBKT;                       // NBKT+1
    uint2* ebuf = (uint2*)x2b;                      // E pairs (dead until kg1)

    const int ntile = (N + 15) / 16;
    const int GB = (ntile + 3) / 4;                 // kgemm blocks (4 tiles each)

    hipLaunchKernelGGL(ksetup, dim3(65), dim3(256), 0, stream,
                       W1, W2, ats2, atd2, w1fh, w1fl, u, v, w2tb);
    hipLaunchKernelGGL(kgemm, dim3(GB), dim3(256), 0, stream,
                       x, w1fh, w1fl, ats1, atd1, h1b, as1, ad1, N, GB);
    hipLaunchKernelGGL(kcnt, dim3(NEB), dim3(256), 0, stream,
                       ei, M, E, NEB, NBKT);
    hipLaunchKernelGGL(kofs, dim3(NBKT), dim3(256), 0, stream, M, tot, NEB);
    hipLaunchKernelGGL(kbase, dim3(1), dim3(256), 0, stream,
                       tot, base, rowptr, NBKT, N, E);
    hipLaunchKernelGGL(kbkt2, dim3(NEB), dim3(256), 0, stream,
                       ei, M, base, ebuf, E, NEB, NBKT);
    hipLaunchKernelGGL(kcsr, dim3(NBKT), dim3(512), 0, stream,
                       ebuf, base, rowptr, colidx, N);
    hipLaunchKernelGGL(kg1, dim3((N + 3) / 4), dim3(256), 0, stream,
                       rowptr, colidx, h1b, as1, ad1, b1, u, v,
                       x2b, as2, ad2, N, E);
    hipLaunchKernelGGL(kh2, dim3((N + 63) / 64), dim3(256), 0, stream,
                       x2b, w2tb, h2b, N);
    hipLaunchKernelGGL(kg2, dim3((N + 3) / 4), dim3(256), 0, stream,
                       rowptr, colidx, h2b, as2, ad2, b2, out, N, E);
}

// Round 8
// 295.703 us; speedup vs baseline: 1.3044x; 1.0105x over previous
//
#include <hip/hip_runtime.h>
#include <hip/hip_bf16.h>
#include <math.h>

// GAT 2-layer. Round 17: dispatch-graph compaction. R16 proved the CSR chain
// internals were not the whale (-6.7us). This round removes serial dispatch
// overhead with zero algorithmic risk: (1) kcnt folded into kgemm as a
// heterogeneous grid (R11-proven pattern) so the histogram runs under the
// GEMM; (2) kbkt2 writes ebuf at fixed per-bucket stride (BSTRIDE=10240,
// 19-sigma headroom over the ~8.2k mean bucket) so it no longer needs the
// base scan; (3) kcsr computes the 196-entry base scan in LDS itself and
// kbase is deleted. 10 dispatches -> 8. kg1/kg2/kh2 byte-identical.

typedef unsigned short u16;
typedef unsigned int u32;
typedef __attribute__((ext_vector_type(8))) short bf16x8;
typedef __attribute__((ext_vector_type(4))) float f32x4;

#define BSTRIDE 10240

__device__ __forceinline__ float eluf(float v) { return v > 0.f ? v : expm1f(v); }
__device__ __forceinline__ u16 f2bf(float f) {
    u32 u = __float_as_uint(f);
    u += 0x7fff + ((u >> 16) & 1);          // RNE
    return (u16)(u >> 16);
}
__device__ __forceinline__ float bf2f(u16 u) {
    return __uint_as_float(((u32)u) << 16);
}
// exp(leaky02(e)) = exp2(e * (e>=0 ? log2e : 0.2*log2e))
__device__ __forceinline__ float expleaky(float e) {
    float m = e >= 0.f ? 1.44269504f : 0.28853901f;
    return exp2f(e * m);
}

// ---------------- ksetup: W1 frag swizzle | W2 prep ------------------------
__global__ __launch_bounds__(256) void ksetup(
    const float* __restrict__ W1, const float* __restrict__ W2,
    const float* __restrict__ ats2, const float* __restrict__ atd2,
    u16* __restrict__ w1fh, u16* __restrict__ w1fl,
    float* __restrict__ u, float* __restrict__ v, u16* __restrict__ w2tb)
{
    const int b = blockIdx.x, tid = threadIdx.x;
    if (b < 64) {
        int idx = b * 256 + tid;
        int j = idx & 7, l = (idx >> 3) & 63, q = (idx >> 9) & 3, ct = idx >> 11;
        int k = q * 32 + (l >> 4) * 8 + j;
        int n = ct * 16 + (l & 15);
        float w = W1[k * 128 + n];
        u16 hv = f2bf(w);
        w1fh[idx] = hv;
        w1fl[idx] = f2bf(w - bf2f(hv));
    } else {
        if (tid < 128) {
            float su = 0.f, sv = 0.f;
            #pragma unroll
            for (int j = 0; j < 16; ++j) {
                float w = W2[tid * 16 + j];
                su = fmaf(w, ats2[j], su);
                sv = fmaf(w, atd2[j], sv);
                w2tb[j * 128 + tid] = f2bf(w);
            }
            u[tid] = su; v[tid] = sv;
        }
    }
}

// ---------------- kgemmc: heterogeneous kcnt + persistent GEMM -------------
// Blocks [0,KB): bucket histogram (M[bkt*NEB+b] = count of dst>>9==bkt in
// edge block b). Blocks [KB,KB+GB): MFMA GEMM with pinned B-fragments.
#define REPW 40   // u16 per repack row (80 B)
__global__ __launch_bounds__(256) void kgemmc(
    const float* __restrict__ x, const u16* __restrict__ w1fh,
    const u16* __restrict__ w1fl,
    const float* __restrict__ att_s, const float* __restrict__ att_d,
    u16* __restrict__ h1b, float* __restrict__ as1, float* __restrict__ ad1,
    int N, int GB,
    const int* __restrict__ ei, int* __restrict__ M,
    int E, int NEB, int NBKT, int KB)
{
    __shared__ u16 rep[4][16 * REPW];
    __shared__ int cnt[256];
    const int tid = threadIdx.x;
    const int b = blockIdx.x;

    if (b < KB) {
        // ---- kcnt role ----
        cnt[tid] = 0;
        __syncthreads();
        const int e0 = b * 2048 + tid;
        int dd[8];
        #pragma unroll
        for (int k = 0; k < 8; ++k) {
            int e = e0 + 256 * k;
            dd[k] = (e < E) ? ei[E + e] : -1;
        }
        #pragma unroll
        for (int k = 0; k < 8; ++k)
            if (dd[k] >= 0) atomicAdd(&cnt[dd[k] >> 9], 1);
        __syncthreads();
        if (tid < NBKT) M[tid * NEB + b] = cnt[tid];
        return;
    }

    const int g = b - KB;
    const int wv = tid >> 6, lane = tid & 63;
    const int m = lane & 15, quad = lane >> 4;
    const int h = wv;                        // head handled by this wave

    // --- B fragments for this head: cts {2h, 2h+1}, hi+lo ---
    bf16x8 bh[2][4], bl[2][4];
    #pragma unroll
    for (int sub = 0; sub < 2; ++sub) {
        #pragma unroll
        for (int q = 0; q < 4; ++q) {
            const int off = (((2 * h + sub) * 4 + q) * 64 + lane) * 8;
            bh[sub][q] = *(const bf16x8*)&w1fh[off];
            bl[sub][q] = *(const bf16x8*)&w1fl[off];
        }
    }
    // Pin the fragments in VGPRs across the tile loop.
    #pragma unroll
    for (int sub = 0; sub < 2; ++sub) {
        #pragma unroll
        for (int q = 0; q < 4; ++q) {
            asm volatile("" : "+v"(bh[sub][q]));
            asm volatile("" : "+v"(bl[sub][q]));
        }
    }

    const float cs0 = att_s[h * 32 + m];
    const float cs1 = att_s[h * 32 + 16 + m];
    const float cd0 = att_d[h * 32 + m];
    const float cd1 = att_d[h * 32 + 16 + m];

    u16* myrep = rep[wv];
    const int ntile = (N + 15) >> 4;

    for (int t = g; t < ntile; t += GB) {
        const int r0 = t << 4;
        int arow = r0 + m;
        if (arow >= N) arow = N - 1;
        const float* xr = &x[(size_t)arow * 128 + quad * 8];

        bf16x8 ah[4], al[4];
        #pragma unroll
        for (int q = 0; q < 4; ++q) {
            float4 f0 = *(const float4*)&xr[q * 32];
            float4 f1 = *(const float4*)&xr[q * 32 + 4];
            float fv[8] = {f0.x, f0.y, f0.z, f0.w, f1.x, f1.y, f1.z, f1.w};
            union { u16 us[8]; bf16x8 v; } hh, lu;
            #pragma unroll
            for (int j = 0; j < 8; ++j) {
                u16 hvv = f2bf(fv[j]);
                hh.us[j] = hvv;
                lu.us[j] = f2bf(fv[j] - bf2f(hvv));
            }
            ah[q] = hh.v; al[q] = lu.v;
        }

        f32x4 acc[2];
        #pragma unroll
        for (int sub = 0; sub < 2; ++sub) {
            f32x4 a = {0.f, 0.f, 0.f, 0.f};
            #pragma unroll
            for (int q = 0; q < 4; ++q) {
                a = __builtin_amdgcn_mfma_f32_16x16x32_bf16(ah[q], bh[sub][q], a, 0, 0, 0);
                a = __builtin_amdgcn_mfma_f32_16x16x32_bf16(al[q], bh[sub][q], a, 0, 0, 0);
                a = __builtin_amdgcn_mfma_f32_16x16x32_bf16(ah[q], bl[sub][q], a, 0, 0, 0);
            }
            acc[sub] = a;
        }

        float sp[4], dp[4];
        #pragma unroll
        for (int r = 0; r < 4; ++r) {
            sp[r] = fmaf(acc[0][r], cs0, acc[1][r] * cs1);
            dp[r] = fmaf(acc[0][r], cd0, acc[1][r] * cd1);
        }
        #pragma unroll
        for (int r = 0; r < 4; ++r) {
            sp[r] += __shfl_xor(sp[r], 1); sp[r] += __shfl_xor(sp[r], 2);
            sp[r] += __shfl_xor(sp[r], 4); sp[r] += __shfl_xor(sp[r], 8);
            dp[r] += __shfl_xor(dp[r], 1); dp[r] += __shfl_xor(dp[r], 2);
            dp[r] += __shfl_xor(dp[r], 4); dp[r] += __shfl_xor(dp[r], 8);
        }
        if (m == 0) {
            #pragma unroll
            for (int r = 0; r < 4; ++r) {
                int rr = r0 + quad * 4 + r;
                if (rr < N) {
                    as1[rr * 4 + h] = sp[r];
                    ad1[rr * 4 + h] = dp[r];
                }
            }
        }

        // repack -> coalesced h1b stores; wave-synchronous LDS slice.
        #pragma unroll
        for (int sub = 0; sub < 2; ++sub) {
            #pragma unroll
            for (int r = 0; r < 4; ++r)
                myrep[(quad * 4 + r) * REPW + sub * 16 + m] = f2bf(acc[sub][r]);
        }
        __asm__ __volatile__("s_waitcnt lgkmcnt(0)" ::: "memory");
        __builtin_amdgcn_sched_barrier(0);
        const int rr = lane >> 2, cc = lane & 3;
        uint4 vv = *(const uint4*)&myrep[rr * REPW + cc * 8];
        const int grow = r0 + rr;
        if (grow < N)
            *(uint4*)&h1b[(size_t)grow * 128 + h * 32 + cc * 8] = vv;
    }
}

// ---------------- kofs: per-bucket exclusive scan over blocks --------------
__global__ __launch_bounds__(256) void kofs(
    int* __restrict__ M, int* __restrict__ tot, int NEB)
{
    __shared__ int lds[256];
    const int bkt = blockIdx.x, t = threadIdx.x;
    int carry = 0;
    const int rounds = (NEB + 255) / 256;
    for (int r = 0; r < rounds; ++r) {
        int idx = r * 256 + t;
        int v = (idx < NEB) ? M[bkt * NEB + idx] : 0;
        lds[t] = v;
        __syncthreads();
        for (int off = 1; off < 256; off <<= 1) {
            int y = (t >= off) ? lds[t - off] : 0;
            __syncthreads();
            lds[t] += y;
            __syncthreads();
        }
        if (idx < NEB) M[bkt * NEB + idx] = carry + lds[t] - v;
        carry += lds[255];
        __syncthreads();
    }
    if (t == 0) tot[bkt] = carry;
}

// ---------------- kbkt2: LDS-staged bucket scatter, fixed stride -----------
__global__ __launch_bounds__(256) void kbkt2(
    const int* __restrict__ ei, const int* __restrict__ M,
    uint2* __restrict__ ebuf, int E, int NEB, int NBKT)
{
    __shared__ int cnt[256], lofs[256], cur[256], boff[256];
    __shared__ uint2 st[2048];
    __shared__ int gp[2048];
    const int b = blockIdx.x, t = threadIdx.x;
    cnt[t] = 0; cur[t] = 0;
    __syncthreads();
    const int e0 = b * 2048 + t;
    int dd[8], ss[8];
    #pragma unroll
    for (int k = 0; k < 8; ++k) {
        int e = e0 + 256 * k;
        if (e < E) { dd[k] = ei[E + e]; ss[k] = ei[e]; } else dd[k] = -1;
    }
    #pragma unroll
    for (int k = 0; k < 8; ++k)
        if (dd[k] >= 0) atomicAdd(&cnt[dd[k] >> 9], 1);
    if (t < NBKT) boff[t] = t * BSTRIDE + M[t * NEB + b];
    __syncthreads();
    // exclusive scan of cnt -> lofs (local bucket starts within stage)
    int v = cnt[t];
    lofs[t] = v;
    __syncthreads();
    for (int off = 1; off < 256; off <<= 1) {
        int y = (t >= off) ? lofs[t - off] : 0;
        __syncthreads();
        lofs[t] += y;
        __syncthreads();
    }
    int excl = lofs[t] - v;
    __syncthreads();
    lofs[t] = excl;
    __syncthreads();
    #pragma unroll
    for (int k = 0; k < 8; ++k) {
        if (dd[k] >= 0) {
            int bkt = dd[k] >> 9;
            int lr = atomicAdd(&cur[bkt], 1);
            int pos = lofs[bkt] + lr;
            st[pos] = make_uint2((u32)dd[k], (u32)ss[k]);
            gp[pos] = boff[bkt] + lr;
        }
    }
    __syncthreads();
    const int nv = min(2048, E - b * 2048);
    for (int i = t; i < nv; i += 256)
        ebuf[gp[i]] = st[i];
}

// ---------------- kcsr: per-bucket CSR build (base scan in-LDS) ------------
#define CSTAGE 8832
__global__ __launch_bounds__(512) void kcsr(
    const uint2* __restrict__ ebuf, const int* __restrict__ tot,
    int* __restrict__ rowptr, int* __restrict__ colidx, int N, int E, int NBKT)
{
    __shared__ int hist[512];
    __shared__ int cur[512];
    __shared__ int bsc[512];
    __shared__ int stage[CSTAGE];
    const int k = blockIdx.x, t = threadIdx.x;
    // base scan of tot[0..NBKT) in LDS (inclusive -> exclusive)
    int tv = (t < NBKT) ? tot[t] : 0;
    bsc[t] = tv;
    __syncthreads();
    for (int off = 1; off < 512; off <<= 1) {
        int y = (t >= off) ? bsc[t - off] : 0;
        __syncthreads();
        bsc[t] += y;
        __syncthreads();
    }
    const int e0 = bsc[k] - tot[k];          // absolute base of this bucket
    const int ne = tot[k];
    const int s0 = k * BSTRIDE;              // ebuf region of this bucket
    const int n0 = k << 9;
    const int nb = min(512, N - n0);
    hist[t] = 0;
    if (k == 0 && t == 0) rowptr[N] = E;
    __syncthreads();
    for (int i = t; i < ne; i += 512)
        atomicAdd(&hist[ebuf[s0 + i].x & 511], 1);
    __syncthreads();
    int v = hist[t];
    for (int off = 1; off < 512; off <<= 1) {
        int y = (t >= off) ? hist[t - off] : 0;
        __syncthreads();
        hist[t] += y;
        __syncthreads();
    }
    int excl = hist[t] - v;
    cur[t] = excl;
    if (t < nb) rowptr[n0 + t] = e0 + excl;
    __syncthreads();
    for (int i = t; i < ne; i += 512) {
        uint2 es = ebuf[s0 + i];
        int r = atomicAdd(&cur[es.x & 511], 1);
        if (r < CSTAGE) stage[r] = (int)es.y;
        else colidx[e0 + r] = (int)es.y;
    }
    __syncthreads();
    const int lim = ne < CSTAGE ? ne : CSTAGE;
    for (int i = t; i < lim; i += 512)
        colidx[e0 + i] = stage[i];
}

// ---------------- KG1: layer-1 gather, in-wave weights ---------------------
__global__ __launch_bounds__(256) void kg1(
    const int* __restrict__ rowptr, const int* __restrict__ colidx,
    const u16* __restrict__ h1b, const float* __restrict__ as1,
    const float* __restrict__ ad1, const float* __restrict__ b1,
    const float* __restrict__ u, const float* __restrict__ v,
    u16* __restrict__ x2b, float* __restrict__ as2, float* __restrict__ ad2,
    int N, int E)
{
    const int d = blockIdx.x * 4 + (threadIdx.x >> 6);
    if (d >= N) return;
    const int lane = threadIdx.x & 63;
    const int c = lane * 2;
    const int headB = lane >> 4;
    const int headA = lane & 3;
    const int eA = lane >> 2;

    const float adA = ad1[d * 4 + headA];
    const float wself = expleaky(as1[d * 4 + headB] + ad1[d * 4 + headB]);
    u32 hd = *(const u32*)&h1b[(d << 7) + c];
    float accx = wself * bf2f((u16)hd);
    float accy = wself * bf2f((u16)(hd >> 16));
    float den = wself;

    int i0r = rowptr[d];
    int i1r = rowptr[d + 1];
    const int i0 = __builtin_amdgcn_readfirstlane(i0r);
    const int i1 = __builtin_amdgcn_readfirstlane(i1r);

    for (int i = i0; i < i1; i += 16) {
        const int nb = min(16, i1 - i);
        const int ii = i + eA;
        const int iic = ii < i1 ? ii : i0;
        int sAv = colidx[iic];
        float wA = expleaky(as1[(sAv << 2) + headA] + adA);
        wA = (ii < i1) ? wA : 0.f;
        int e = 0;
        for (; e + 8 <= nb; e += 8) {
            int s0 = colidx[i + e + 0];
            int s1 = colidx[i + e + 1];
            int s2 = colidx[i + e + 2];
            int s3 = colidx[i + e + 3];
            int s4 = colidx[i + e + 4];
            int s5 = colidx[i + e + 5];
            int s6 = colidx[i + e + 6];
            int s7 = colidx[i + e + 7];
            float w0 = __shfl(wA, ((e + 0) << 2) + headB);
            float w1 = __shfl(wA, ((e + 1) << 2) + headB);
            float w2 = __shfl(wA, ((e + 2) << 2) + headB);
            float w3 = __shfl(wA, ((e + 3) << 2) + headB);
            float w4 = __shfl(wA, ((e + 4) << 2) + headB);
            float w5 = __shfl(wA, ((e + 5) << 2) + headB);
            float w6 = __shfl(wA, ((e + 6) << 2) + headB);
            float w7 = __shfl(wA, ((e + 7) << 2) + headB);
            u32 v0 = *(const u32*)&h1b[(s0 << 7) + c];
            u32 v1 = *(const u32*)&h1b[(s1 << 7) + c];
            u32 v2 = *(const u32*)&h1b[(s2 << 7) + c];
            u32 v3 = *(const u32*)&h1b[(s3 << 7) + c];
            u32 v4 = *(const u32*)&h1b[(s4 << 7) + c];
            u32 v5 = *(const u32*)&h1b[(s5 << 7) + c];
            u32 v6 = *(const u32*)&h1b[(s6 << 7) + c];
            u32 v7 = *(const u32*)&h1b[(s7 << 7) + c];
            accx = fmaf(w0, bf2f((u16)v0), accx); accy = fmaf(w0, bf2f((u16)(v0 >> 16)), accy);
            accx = fmaf(w1, bf2f((u16)v1), accx); accy = fmaf(w1, bf2f((u16)(v1 >> 16)), accy);
            accx = fmaf(w2, bf2f((u16)v2), accx); accy = fmaf(w2, bf2f((u16)(v2 >> 16)), accy);
            accx = fmaf(w3, bf2f((u16)v3), accx); accy = fmaf(w3, bf2f((u16)(v3 >> 16)), accy);
            accx = fmaf(w4, bf2f((u16)v4), accx); accy = fmaf(w4, bf2f((u16)(v4 >> 16)), accy);
            accx = fmaf(w5, bf2f((u16)v5), accx); accy = fmaf(w5, bf2f((u16)(v5 >> 16)), accy);
            accx = fmaf(w6, bf2f((u16)v6), accx); accy = fmaf(w6, bf2f((u16)(v6 >> 16)), accy);
            accx = fmaf(w7, bf2f((u16)v7), accx); accy = fmaf(w7, bf2f((u16)(v7 >> 16)), accy);
            den += ((w0 + w1) + (w2 + w3)) + ((w4 + w5) + (w6 + w7));
        }
        for (; e < nb; ++e) {
            int s = colidx[i + e];
            float w = __shfl(wA, (e << 2) + headB);
            u32 hv = *(const u32*)&h1b[(s << 7) + c];
            accx = fmaf(w, bf2f((u16)hv), accx);
            accy = fmaf(w, bf2f((u16)(hv >> 16)), accy);
            den += w;
        }
    }

    const float inv = 1.f / den;
    const float2 bv = *(const float2*)&b1[c];
    const float x2a = eluf(fmaf(accx, inv, bv.x));
    const float x2c = eluf(fmaf(accy, inv, bv.y));

    u32 pk = ((u32)f2bf(x2c) << 16) | (u32)f2bf(x2a);
    *(u32*)&x2b[(d << 7) + c] = pk;

    const float2 uv = *(const float2*)&u[c];
    const float2 vv = *(const float2*)&v[c];
    float sA = fmaf(x2a, uv.x, x2c * uv.y);
    float sB = fmaf(x2a, vv.x, x2c * vv.y);
    #pragma unroll
    for (int m = 1; m < 64; m <<= 1) {
        sA += __shfl_xor(sA, m);
        sB += __shfl_xor(sB, m);
    }
    if (lane == 0) { as2[d] = sA; ad2[d] = sB; }
}

// ---------------- KH2: h2 = x2 @ W2 via MFMA (bf16 out) --------------------
__global__ __launch_bounds__(256) void kh2(
    const u16* __restrict__ x2b, const u16* __restrict__ w2tb,
    u16* __restrict__ h2b, int N)
{
    const int wv = threadIdx.x >> 6, lane = threadIdx.x & 63;
    const int n0 = blockIdx.x * 64 + wv * 16;
    if (n0 >= N) return;
    const int m = lane & 15;
    const int kq = lane >> 4;
    bf16x8 bfr[4];
    #pragma unroll
    for (int q = 0; q < 4; ++q)
        bfr[q] = *(const bf16x8*)&w2tb[m * 128 + q * 32 + kq * 8];

    int ar = n0 + m;
    if (ar >= N) ar = N - 1;
    const u16* arow = &x2b[((size_t)ar << 7) + kq * 8];
    f32x4 acc = {0.f, 0.f, 0.f, 0.f};
    #pragma unroll
    for (int q = 0; q < 4; ++q) {
        bf16x8 af = *(const bf16x8*)&arow[q * 32];
        acc = __builtin_amdgcn_mfma_f32_16x16x32_bf16(af, bfr[q], acc, 0, 0, 0);
    }
    #pragma unroll
    for (int r = 0; r < 4; ++r) {
        int rr = n0 + kq * 4 + r;
        if (rr < N) h2b[((size_t)rr << 4) + m] = f2bf(acc[r]);
    }
}

// ---------------- KG2: layer-2 gather, in-wave weights ---------------------
__global__ __launch_bounds__(256) void kg2(
    const int* __restrict__ rowptr, const int* __restrict__ colidx,
    const u16* __restrict__ h2b, const float* __restrict__ as2,
    const float* __restrict__ ad2, const float* __restrict__ b2,
    float* __restrict__ out, int N, int E)
{
    const int d = blockIdx.x * 4 + (threadIdx.x >> 6);
    if (d >= N) return;
    const int lane = threadIdx.x & 63;
    const int ch = lane & 7, g = lane >> 3;

    const float ad_d = ad2[d];
    float acc0 = 0.f, acc1 = 0.f, den = 0.f;
    int i0r = rowptr[d];
    int i1r = rowptr[d + 1];
    const int i0 = __builtin_amdgcn_readfirstlane(i0r);
    const int i1 = __builtin_amdgcn_readfirstlane(i1r);

    for (int i = i0; i < i1; i += 64) {
        const int nb = min(64, i1 - i);
        const int idx = i + lane;
        const int idxc = idx < i1 ? idx : i0;
        int sA = colidx[idxc];
        float wA = expleaky(as2[sA] + ad_d);
        wA = (idx < i1) ? wA : 0.f;
        const int kU = (nb + 7) >> 3;
        for (int k = 0; k < kU; ++k) {
            int e = g + 8 * k;
            int ec = e < nb ? e : 0;
            float w = __shfl(wA, ec);
            int s = __shfl(sA, ec);
            if (e >= nb) w = 0.f;
            u32 hv = *(const u32*)&h2b[(s << 4) + ch * 2];
            acc0 = fmaf(w, bf2f((u16)hv), acc0);
            acc1 = fmaf(w, bf2f((u16)(hv >> 16)), acc1);
            den += w;
        }
    }
    acc0 += __shfl_xor(acc0, 8); acc0 += __shfl_xor(acc0, 16); acc0 += __shfl_xor(acc0, 32);
    acc1 += __shfl_xor(acc1, 8); acc1 += __shfl_xor(acc1, 16); acc1 += __shfl_xor(acc1, 32);
    den  += __shfl_xor(den, 8);  den  += __shfl_xor(den, 16);  den  += __shfl_xor(den, 32);

    const float wself = expleaky(as2[d] + ad_d);
    u32 hd = *(const u32*)&h2b[(d << 4) + ch * 2];
    acc0 = fmaf(wself, bf2f((u16)hd), acc0);
    acc1 = fmaf(wself, bf2f((u16)(hd >> 16)), acc1);
    den += wself;
    if (g == 0) {
        float2 ov = {acc0 / den + b2[ch * 2], acc1 / den + b2[ch * 2 + 1]};
        *(float2*)&out[(d << 4) + ch * 2] = ov;
    }
}

extern "C" void kernel_launch(void* const* d_in, const int* in_sizes, int n_in,
                              void* d_out, int out_size, void* d_ws, size_t ws_size,
                              hipStream_t stream) {
    const float* x    = (const float*)d_in[0];
    const int*   ei   = (const int*)d_in[1];
    const float* W1   = (const float*)d_in[2];
    const float* ats1 = (const float*)d_in[3];
    const float* atd1 = (const float*)d_in[4];
    const float* b1   = (const float*)d_in[5];
    const float* W2   = (const float*)d_in[6];
    const float* ats2 = (const float*)d_in[7];
    const float* atd2 = (const float*)d_in[8];
    const float* b2   = (const float*)d_in[9];
    float* out = (float*)d_out;
    const int N = in_sizes[0] / 128;
    const int E = in_sizes[1] / 2;

    const int NEB  = (E + 2047) / 2048;             // edge blocks (782)
    const int NBKT = (N + 511) >> 9;                // node buckets (196)

    u16* h1b   = (u16*)d_ws;                        // 128N
    u16* x2b   = h1b + (size_t)N * 128;             // 128N (ebuf aliases)
    u16* h2b   = x2b + (size_t)N * 128;             // 16N
    u16* w2tb  = h2b + (size_t)N * 16;              // 2048
    u16* w1fh  = w2tb + 2048;                       // 16384
    u16* w1fl  = w1fh + 16384;                      // 16384
    float* as1 = (float*)(w1fl + 16384);            // 4N
    float* ad1 = as1 + (size_t)N * 4;               // 4N
    float* as2 = ad1 + (size_t)N * 4;               // N
    float* ad2 = as2 + N;                           // N
    float* u   = ad2 + N;                           // 128
    float* v   = u + 128;                           // 128
    int* rowptr = (int*)(v + 128);                  // N+1 (padded)
    int* colidx = rowptr + ((N + 8) & ~3);          // E
    int* M      = colidx + E;                       // NBKT*NEB
    int* tot    = M + (size_t)NBKT * NEB;           // NBKT
    uint2* ebuf = (uint2*)x2b;                      // NBKT*BSTRIDE pairs (16.06MB <= 25.6MB)

    const int ntile = (N + 15) / 16;
    const int GB = (ntile + 3) / 4;                 // GEMM blocks (4 tiles each)
    const int KB = NEB;                             // kcnt blocks

    hipLaunchKernelGGL(ksetup, dim3(65), dim3(256), 0, stream,
                       W1, W2, ats2, atd2, w1fh, w1fl, u, v, w2tb);
    hipLaunchKernelGGL(kgemmc, dim3(KB + GB), dim3(256), 0, stream,
                       x, w1fh, w1fl, ats1, atd1, h1b, as1, ad1, N, GB,
                       ei, M, E, NEB, NBKT, KB);
    hipLaunchKernelGGL(kofs, dim3(NBKT), dim3(256), 0, stream, M, tot, NEB);
    hipLaunchKernelGGL(kbkt2, dim3(NEB), dim3(256), 0, stream,
                       ei, M, ebuf, E, NEB, NBKT);
    hipLaunchKernelGGL(kcsr, dim3(NBKT), dim3(512), 0, stream,
                       ebuf, tot, rowptr, colidx, N, E, NBKT);
    hipLaunchKernelGGL(kg1, dim3((N + 3) / 4), dim3(256), 0, stream,
                       rowptr, colidx, h1b, as1, ad1, b1, u, v,
                       x2b, as2, ad2, N, E);
    hipLaunchKernelGGL(kh2, dim3((N + 63) / 64), dim3(256), 0, stream,
                       x2b, w2tb, h2b, N);
    hipLaunchKernelGGL(kg2, dim3((N + 3) / 4), dim3(256), 0, stream,
                       rowptr, colidx, h2b, as2, ad2, b2, out, N, E);
}